// Round 1
// baseline (386.178 us; speedup 1.0000x reference)
//
#include <hip/hip_runtime.h>
#include <math.h>

// Problem constants
// B=256, H=W=64, P=16, PH=PW=16, ZD=32, HD=1024, UD=3, IN=4096
// Split-K factor for the two MLP GEMMs
#define SPLITK 8

// ---------------------------------------------------------------------------
// GEMM (fp32, split-K): C_partial[s] = A[256,K_chunk] @ W[K_chunk,1024]
// Block: 64x64 tile, 256 threads, 4x4 micro-tile per thread.
// grid = (N/64=16, M/64=4, SPLITK)
// ---------------------------------------------------------------------------
__global__ __launch_bounds__(256) void gemm_splitk(
    const float* __restrict__ A, const float* __restrict__ W,
    float* __restrict__ psum, int K, int kchunk)
{
    const int N = 1024;
    __shared__ __align__(16) float As[16][64];
    __shared__ __align__(16) float Bs[16][64];
    int tid = threadIdx.x;
    int n0 = blockIdx.x * 64;
    int m0 = blockIdx.y * 64;
    int k_begin = blockIdx.z * kchunk;

    int tx = tid & 15, ty = tid >> 4;
    int am = tid >> 2, ak = (tid & 3) << 2;   // A tile load: row am, 4 k's
    int wk = tid >> 4, wn = (tid & 15) << 2;  // W tile load: k row wk, 4 n's

    float acc[4][4] = {};

    for (int k0 = k_begin; k0 < k_begin + kchunk; k0 += 16) {
        float4 av = *(const float4*)(A + (m0 + am) * K + (k0 + ak));
        float4 wv = *(const float4*)(W + (k0 + wk) * N + (n0 + wn));
        __syncthreads();
        As[ak + 0][am] = av.x;
        As[ak + 1][am] = av.y;
        As[ak + 2][am] = av.z;
        As[ak + 3][am] = av.w;
        *(float4*)&Bs[wk][wn] = wv;
        __syncthreads();
#pragma unroll
        for (int kk = 0; kk < 16; kk++) {
            float4 a4 = *(const float4*)&As[kk][ty << 2];
            float4 b4 = *(const float4*)&Bs[kk][tx << 2];
            acc[0][0] = fmaf(a4.x, b4.x, acc[0][0]);
            acc[0][1] = fmaf(a4.x, b4.y, acc[0][1]);
            acc[0][2] = fmaf(a4.x, b4.z, acc[0][2]);
            acc[0][3] = fmaf(a4.x, b4.w, acc[0][3]);
            acc[1][0] = fmaf(a4.y, b4.x, acc[1][0]);
            acc[1][1] = fmaf(a4.y, b4.y, acc[1][1]);
            acc[1][2] = fmaf(a4.y, b4.z, acc[1][2]);
            acc[1][3] = fmaf(a4.y, b4.w, acc[1][3]);
            acc[2][0] = fmaf(a4.z, b4.x, acc[2][0]);
            acc[2][1] = fmaf(a4.z, b4.y, acc[2][1]);
            acc[2][2] = fmaf(a4.z, b4.z, acc[2][2]);
            acc[2][3] = fmaf(a4.z, b4.w, acc[2][3]);
            acc[3][0] = fmaf(a4.w, b4.x, acc[3][0]);
            acc[3][1] = fmaf(a4.w, b4.y, acc[3][1]);
            acc[3][2] = fmaf(a4.w, b4.z, acc[3][2]);
            acc[3][3] = fmaf(a4.w, b4.w, acc[3][3]);
        }
    }

    float* op = psum + (size_t)blockIdx.z * (256 * 1024);
#pragma unroll
    for (int r = 0; r < 4; r++) {
        float4 v = make_float4(acc[r][0], acc[r][1], acc[r][2], acc[r][3]);
        *(float4*)(op + (m0 + (ty << 2) + r) * N + n0 + (tx << 2)) = v;
    }
}

// ---------------------------------------------------------------------------
// Reduce split-K partials + bias + relu.  total = 256*1024 elements.
// ---------------------------------------------------------------------------
__global__ __launch_bounds__(256) void reduce_bias_relu(
    const float* __restrict__ psum, const float* __restrict__ bias,
    float* __restrict__ out)
{
    int i = blockIdx.x * 256 + threadIdx.x;
    float v = 0.f;
#pragma unroll
    for (int s = 0; s < SPLITK; s++) v += psum[(size_t)s * 262144 + i];
    v += bias[i & 1023];
    out[i] = fmaxf(v, 0.f);
}

// ---------------------------------------------------------------------------
// Small heads: umu/uvar (48 cols), gmu/gvar (3 cols), sample u and gu.
// One block per batch element, 128 threads.
// ---------------------------------------------------------------------------
__global__ __launch_bounds__(128) void heads_kernel(
    const float* __restrict__ hid,
    const float* __restrict__ Wum, const float* __restrict__ bum,
    const float* __restrict__ Wuv, const float* __restrict__ buv,
    const float* __restrict__ Wgm, const float* __restrict__ bgm,
    const float* __restrict__ Wgv, const float* __restrict__ bgv,
    const float* __restrict__ eps_u, const float* __restrict__ eps_g,
    float* __restrict__ u_out, float* __restrict__ gu_out)
{
    __shared__ float h[1024];
    int b = blockIdx.x, tid = threadIdx.x;
    for (int i = tid; i < 1024; i += 128) h[i] = hid[b * 1024 + i];
    __syncthreads();
    if (tid < 48) {
        float accm = 0.f, accv = 0.f;
#pragma unroll 8
        for (int k = 0; k < 1024; k++) {
            float hv = h[k];
            accm = fmaf(hv, Wum[k * 48 + tid], accm);
            accv = fmaf(hv, Wuv[k * 48 + tid], accv);
        }
        float umu = tanhf(accm + bum[tid]);
        float upre = accv + buv[tid];
        // F.threshold(x,-6,-6): x>-6 ? x : -6  == max(x,-6)
        float uvar = expf(fmaxf(upre, -6.f));
        u_out[b * 48 + tid] = umu + uvar * eps_u[b * 48 + tid];
    } else if (tid < 51) {
        int n = tid - 48;
        float accm = 0.f, accv = 0.f;
#pragma unroll 8
        for (int k = 0; k < 1024; k++) {
            float hv = h[k];
            accm = fmaf(hv, Wgm[k * 3 + n], accm);
            accv = fmaf(hv, Wgv[k * 3 + n], accv);
        }
        float gmu = tanhf(accm + bgm[n]);
        float gpre = accv + bgv[n];
        // F.threshold(x,-6,6): x>-6 ? x : 6   (note: 6, not -6!)
        float gvar = expf(gpre > -6.f ? gpre : 6.f);
        gu_out[b * 3 + n] = gmu + gvar * eps_g[b * 3 + n];
    }
}

// ---------------------------------------------------------------------------
// Parts: sigmoid of column-sums of Wz [32,4096] -> 16 patches of 16x16.
// (ones(B,ZD) @ Wz makes every batch row identical.)
// ---------------------------------------------------------------------------
__global__ __launch_bounds__(256) void parts_kernel(
    const float* __restrict__ Wz, float* __restrict__ out)
{
    int idx = blockIdx.x * 256 + threadIdx.x;  // 0..4095
    float s = 0.f;
#pragma unroll
    for (int z = 0; z < 32; z++) s += Wz[z * 4096 + idx];
    out[idx] = 1.f / (1.f + expf(-s));
}

// ---------------------------------------------------------------------------
// Composite: for each (b,i,j), loop p=0..15:
//   km = bilinear(M[b*16+p] anchor-shifted, translation u)   [fused int shift]
//   xp = bilinear(part patch at anchor offset, rotation+translation u)
//   num += xp*km; den += km;   x = num / (den==0?1:den)
// grid = (256 batches, 4 row-chunks), 256 threads, 4 pixels/thread.
// ---------------------------------------------------------------------------
__global__ __launch_bounds__(256) void composite_kernel(
    const float* __restrict__ M, const float* __restrict__ parts,
    const float* __restrict__ u, float* __restrict__ xout)
{
    __shared__ float patch[16 * 256];
    __shared__ float pc[16], psn[16], ptx[16], pty[16];
    int b = blockIdx.x;
    int tid = threadIdx.x;
    for (int i = tid; i < 4096; i += 256) patch[i] = parts[i];
    if (tid < 16) {
        const float* up = u + (b * 16 + tid) * 3;
        float ang = up[0];
        pc[tid] = cosf(ang);
        psn[tid] = sinf(ang);
        ptx[tid] = up[1];
        pty[tid] = up[2];
    }
    __syncthreads();

    for (int t = 0; t < 4; t++) {
        int pix = blockIdx.y * 1024 + t * 256 + tid;
        int ii = pix >> 6, jj = pix & 63;
        float xn = (float)(2 * jj + 1) * (1.f / 64.f) - 1.f;
        float yn = (float)(2 * ii + 1) * (1.f / 64.f) - 1.f;
        float num = 0.f, den = 0.f;
#pragma unroll
        for (int p = 0; p < 16; p++) {
            int dx = 8 * (p & 3) - 12;
            int dy = 8 * (p >> 2) - 12;
            float c = pc[p], s = psn[p], tx = ptx[p], ty = pty[p];
            // ---- KM: translation-only sample of anchor-shifted M ----
            float km;
            {
                float gx = xn + tx;
                float gy = yn + ty;
                float xs = (gx + 1.f) * 32.f - 0.5f;
                float ysv = (gy + 1.f) * 32.f - 0.5f;
                float xf = floorf(xs), yf = floorf(ysv);
                float wx = xs - xf, wy = ysv - yf;
                int x0 = (int)xf, y0 = (int)yf;
                const float* Mp = M + ((size_t)(b * 16 + p) << 12);
                int lox = dx < 0 ? -dx : 0;
                int hix = dx > 0 ? 64 - dx : 64;
                int loy = dy < 0 ? -dy : 0;
                int hiy = dy > 0 ? 64 - dy : 64;
                float v00 = 0.f, v10 = 0.f, v01 = 0.f, v11 = 0.f;
                bool vx0 = (x0 >= lox) && (x0 < hix);
                bool vx1 = (x0 + 1 >= lox) && (x0 + 1 < hix);
                if ((y0 >= loy) && (y0 < hiy)) {
                    const float* row = Mp + (y0 + dy) * 64 + dx;
                    if (vx0) v00 = row[x0];
                    if (vx1) v10 = row[x0 + 1];
                }
                if ((y0 + 1 >= loy) && (y0 + 1 < hiy)) {
                    const float* row = Mp + (y0 + 1 + dy) * 64 + dx;
                    if (vx0) v01 = row[x0];
                    if (vx1) v11 = row[x0 + 1];
                }
                km = v00 * (1.f - wx) * (1.f - wy) + v10 * wx * (1.f - wy)
                   + v01 * (1.f - wx) * wy + v11 * wx * wy;
            }
            // ---- xp: rotation+translation sample of anchored part patch ----
            float xp;
            {
                float gx = c * xn - s * yn + tx;
                float gy = s * xn + c * yn + ty;
                float xs = (gx + 1.f) * 32.f - 0.5f;
                float ysv = (gy + 1.f) * 32.f - 0.5f;
                float xf = floorf(xs), yf = floorf(ysv);
                float wx = xs - xf, wy = ysv - yf;
                int x0 = (int)xf, y0 = (int)yf;
                int ox = 24 - dx, oy = 24 - dy;  // patch origin in anchored image
                int a0 = y0 - oy, a1 = a0 + 1;
                int b0 = x0 - ox, b1c = b0 + 1;
                const float* pp = patch + p * 256;
                float v00 = 0.f, v10 = 0.f, v01 = 0.f, v11 = 0.f;
                if ((unsigned)a0 < 16u) {
                    if ((unsigned)b0 < 16u) v00 = pp[a0 * 16 + b0];
                    if ((unsigned)b1c < 16u) v10 = pp[a0 * 16 + b1c];
                }
                if ((unsigned)a1 < 16u) {
                    if ((unsigned)b0 < 16u) v01 = pp[a1 * 16 + b0];
                    if ((unsigned)b1c < 16u) v11 = pp[a1 * 16 + b1c];
                }
                xp = v00 * (1.f - wx) * (1.f - wy) + v10 * wx * (1.f - wy)
                   + v01 * (1.f - wx) * wy + v11 * wx * wy;
            }
            num += xp * km;
            den += km;
        }
        float d = (den == 0.f) ? 1.f : den;
        xout[(size_t)b * 4096 + pix] = num / d;
    }
}

// ---------------------------------------------------------------------------
// Final global transform: out[b] = bilinear(x[b], rot_tr(gu[b]) grid)
// ---------------------------------------------------------------------------
__global__ __launch_bounds__(256) void final_kernel(
    const float* __restrict__ xin, const float* __restrict__ gu,
    float* __restrict__ out)
{
    int id = blockIdx.x * 256 + threadIdx.x;  // 1048576
    int b = id >> 12;
    int pix = id & 4095;
    int ii = pix >> 6, jj = pix & 63;
    float ang = gu[b * 3 + 0], tx = gu[b * 3 + 1], ty = gu[b * 3 + 2];
    float c = cosf(ang), s = sinf(ang);
    float xn = (float)(2 * jj + 1) * (1.f / 64.f) - 1.f;
    float yn = (float)(2 * ii + 1) * (1.f / 64.f) - 1.f;
    float gx = c * xn - s * yn + tx;
    float gy = s * xn + c * yn + ty;
    float xs = (gx + 1.f) * 32.f - 0.5f;
    float ysv = (gy + 1.f) * 32.f - 0.5f;
    float xf = floorf(xs), yf = floorf(ysv);
    float wx = xs - xf, wy = ysv - yf;
    int x0 = (int)xf, y0 = (int)yf;
    const float* xp = xin + ((size_t)b << 12);
    float v00 = 0.f, v10 = 0.f, v01 = 0.f, v11 = 0.f;
    bool vx0 = (unsigned)x0 < 64u, vx1 = (unsigned)(x0 + 1) < 64u;
    if ((unsigned)y0 < 64u) {
        if (vx0) v00 = xp[y0 * 64 + x0];
        if (vx1) v10 = xp[y0 * 64 + x0 + 1];
    }
    if ((unsigned)(y0 + 1) < 64u) {
        if (vx0) v01 = xp[(y0 + 1) * 64 + x0];
        if (vx1) v11 = xp[(y0 + 1) * 64 + x0 + 1];
    }
    out[id] = v00 * (1.f - wx) * (1.f - wy) + v10 * wx * (1.f - wy)
            + v01 * (1.f - wx) * wy + v11 * wx * wy;
}

// ---------------------------------------------------------------------------
extern "C" void kernel_launch(void* const* d_in, const int* in_sizes, int n_in,
                              void* d_out, int out_size, void* d_ws, size_t ws_size,
                              hipStream_t stream)
{
    (void)in_sizes; (void)n_in; (void)out_size; (void)ws_size;
    const float* inputs = (const float*)d_in[0];
    const float* W1  = (const float*)d_in[1];
    const float* b1  = (const float*)d_in[2];
    const float* W2  = (const float*)d_in[3];
    const float* b2  = (const float*)d_in[4];
    const float* Wum = (const float*)d_in[5];
    const float* bum = (const float*)d_in[6];
    const float* Wuv = (const float*)d_in[7];
    const float* buv = (const float*)d_in[8];
    const float* Wgm = (const float*)d_in[9];
    const float* bgm = (const float*)d_in[10];
    const float* Wgv = (const float*)d_in[11];
    const float* bgv = (const float*)d_in[12];
    const float* Wz  = (const float*)d_in[13];
    const float* Mm  = (const float*)d_in[14];
    const float* eps_u = (const float*)d_in[15];
    const float* eps_g = (const float*)d_in[16];

    float* ws = (float*)d_ws;
    float* hid1      = ws;                        // 262144
    float* hid2      = ws + 262144;               // 262144
    float* psum      = ws + 524288;               // SPLITK*262144 = 2097152
    float* u_buf     = ws + 524288 + SPLITK * 262144;        // 12288
    float* gu_buf    = u_buf + 12288;             // 768
    float* parts_buf = gu_buf + 768;              // 4096
    float* x_buf     = parts_buf + 4096;          // 1048576

    // MLP layer 1: [256,4096] @ [4096,1024]
    gemm_splitk<<<dim3(16, 4, SPLITK), 256, 0, stream>>>(inputs, W1, psum, 4096, 4096 / SPLITK);
    reduce_bias_relu<<<1024, 256, 0, stream>>>(psum, b1, hid1);
    // MLP layer 2: [256,1024] @ [1024,1024]
    gemm_splitk<<<dim3(16, 4, SPLITK), 256, 0, stream>>>(hid1, W2, psum, 1024, 1024 / SPLITK);
    reduce_bias_relu<<<1024, 256, 0, stream>>>(psum, b2, hid2);
    // Heads -> u [4096,3], gu [256,3]
    heads_kernel<<<256, 128, 0, stream>>>(hid2, Wum, bum, Wuv, buv, Wgm, bgm,
                                          Wgv, bgv, eps_u, eps_g, u_buf, gu_buf);
    // Part patches (batch-independent)
    parts_kernel<<<16, 256, 0, stream>>>(Wz, parts_buf);
    // Masked compositing -> x [256,64,64]
    composite_kernel<<<dim3(256, 4), 256, 0, stream>>>(Mm, parts_buf, u_buf, x_buf);
    // Global transform -> out [256,1,64,64]
    final_kernel<<<4096, 256, 0, stream>>>(x_buf, gu_buf, (float*)d_out);
}

// Round 2
// 330.386 us; speedup vs baseline: 1.1689x; 1.1689x over previous
//
#include <hip/hip_runtime.h>
#include <math.h>

// Problem constants
// B=256, H=W=64, P=16, PH=PW=16, ZD=32, HD=1024, UD=3, IN=4096
#define SPLITK 8

// ---------------------------------------------------------------------------
// GEMM (fp32, split-K): C_partial[s] = A[256,K_chunk] @ W[K_chunk,1024]
// Block: 64x64 tile, 256 threads, 4x4 micro-tile per thread.
// grid = (N/64=16, M/64=4, SPLITK)
// ---------------------------------------------------------------------------
__global__ __launch_bounds__(256) void gemm_splitk(
    const float* __restrict__ A, const float* __restrict__ W,
    float* __restrict__ psum, int K, int kchunk)
{
    const int N = 1024;
    __shared__ __align__(16) float As[16][64];
    __shared__ __align__(16) float Bs[16][64];
    int tid = threadIdx.x;
    int n0 = blockIdx.x * 64;
    int m0 = blockIdx.y * 64;
    int k_begin = blockIdx.z * kchunk;

    int tx = tid & 15, ty = tid >> 4;
    int am = tid >> 2, ak = (tid & 3) << 2;   // A tile load: row am, 4 k's
    int wk = tid >> 4, wn = (tid & 15) << 2;  // W tile load: k row wk, 4 n's

    float acc[4][4] = {};

    for (int k0 = k_begin; k0 < k_begin + kchunk; k0 += 16) {
        float4 av = *(const float4*)(A + (m0 + am) * K + (k0 + ak));
        float4 wv = *(const float4*)(W + (k0 + wk) * N + (n0 + wn));
        __syncthreads();
        As[ak + 0][am] = av.x;
        As[ak + 1][am] = av.y;
        As[ak + 2][am] = av.z;
        As[ak + 3][am] = av.w;
        *(float4*)&Bs[wk][wn] = wv;
        __syncthreads();
#pragma unroll
        for (int kk = 0; kk < 16; kk++) {
            float4 a4 = *(const float4*)&As[kk][ty << 2];
            float4 b4 = *(const float4*)&Bs[kk][tx << 2];
            acc[0][0] = fmaf(a4.x, b4.x, acc[0][0]);
            acc[0][1] = fmaf(a4.x, b4.y, acc[0][1]);
            acc[0][2] = fmaf(a4.x, b4.z, acc[0][2]);
            acc[0][3] = fmaf(a4.x, b4.w, acc[0][3]);
            acc[1][0] = fmaf(a4.y, b4.x, acc[1][0]);
            acc[1][1] = fmaf(a4.y, b4.y, acc[1][1]);
            acc[1][2] = fmaf(a4.y, b4.z, acc[1][2]);
            acc[1][3] = fmaf(a4.y, b4.w, acc[1][3]);
            acc[2][0] = fmaf(a4.z, b4.x, acc[2][0]);
            acc[2][1] = fmaf(a4.z, b4.y, acc[2][1]);
            acc[2][2] = fmaf(a4.z, b4.z, acc[2][2]);
            acc[2][3] = fmaf(a4.z, b4.w, acc[2][3]);
            acc[3][0] = fmaf(a4.w, b4.x, acc[3][0]);
            acc[3][1] = fmaf(a4.w, b4.y, acc[3][1]);
            acc[3][2] = fmaf(a4.w, b4.z, acc[3][2]);
            acc[3][3] = fmaf(a4.w, b4.w, acc[3][3]);
        }
    }

    float* op = psum + (size_t)blockIdx.z * (256 * 1024);
#pragma unroll
    for (int r = 0; r < 4; r++) {
        float4 v = make_float4(acc[r][0], acc[r][1], acc[r][2], acc[r][3]);
        *(float4*)(op + (m0 + (ty << 2) + r) * N + n0 + (tx << 2)) = v;
    }
}

// ---------------------------------------------------------------------------
// Reduce split-K partials + bias + relu.  total = 256*1024 elements.
// ---------------------------------------------------------------------------
__global__ __launch_bounds__(256) void reduce_bias_relu(
    const float* __restrict__ psum, const float* __restrict__ bias,
    float* __restrict__ out)
{
    int i = blockIdx.x * 256 + threadIdx.x;
    float v = 0.f;
#pragma unroll
    for (int s = 0; s < SPLITK; s++) v += psum[(size_t)s * 262144 + i];
    v += bias[i & 1023];
    out[i] = fmaxf(v, 0.f);
}

// ---------------------------------------------------------------------------
// Transpose head weights into k-major WT[102][1024]:
//   rows 0..47  = Wum columns, rows 48..95 = Wuv columns,
//   rows 96..98 = Wgm columns, rows 99..101 = Wgv columns.
// ---------------------------------------------------------------------------
__global__ __launch_bounds__(256) void transpose_heads(
    const float* __restrict__ Wum, const float* __restrict__ Wuv,
    const float* __restrict__ Wgm, const float* __restrict__ Wgv,
    float* __restrict__ WT)
{
    int id = blockIdx.x * 256 + threadIdx.x;   // 102*1024 = 104448
    int o = id >> 10;
    int k = id & 1023;
    float v;
    if (o < 48)       v = Wum[k * 48 + o];
    else if (o < 96)  v = Wuv[k * 48 + (o - 48)];
    else if (o < 99)  v = Wgm[k * 3 + (o - 96)];
    else              v = Wgv[k * 3 + (o - 99)];
    WT[id] = v;
}

// ---------------------------------------------------------------------------
// Heads: 51 logical outputs per batch, each = two 1024-dots (mu-row, var-row).
// Block = 512 threads (8 waves) handles 2 batches; wave w does outputs
// o = w, w+8, ...  Lanes split k (stride 64, coalesced WT loads, conflict-free
// LDS h reads), butterfly shfl reduce, lanes 0/1 finish batch 0/1.
// ---------------------------------------------------------------------------
__global__ __launch_bounds__(512) void heads_compute(
    const float* __restrict__ hid, const float* __restrict__ WT,
    const float* __restrict__ bum, const float* __restrict__ buv,
    const float* __restrict__ bgm, const float* __restrict__ bgv,
    const float* __restrict__ eps_u, const float* __restrict__ eps_g,
    float* __restrict__ u_out, float* __restrict__ gu_out)
{
    __shared__ float h[2048];
    int b0 = blockIdx.x << 1;
    int tid = threadIdx.x;
    const float* hp = hid + b0 * 1024;
    for (int i = tid; i < 2048; i += 512) h[i] = hp[i];
    __syncthreads();
    int w = tid >> 6, l = tid & 63;
    for (int o = w; o < 51; o += 8) {
        int rm = (o < 48) ? o : (48 + o);        // mu row:  o  or 96+(o-48)
        int rv = (o < 48) ? (o + 48) : (51 + o); // var row: 48+o or 99+(o-48)
        const float* wmp = WT + rm * 1024;
        const float* wvp = WT + rv * 1024;
        float am0 = 0.f, am1 = 0.f, av0 = 0.f, av1 = 0.f;
#pragma unroll
        for (int j0 = 0; j0 < 1024; j0 += 64) {
            int j = j0 + l;
            float wm = wmp[j], wv = wvp[j];
            float h0 = h[j], h1 = h[1024 + j];
            am0 = fmaf(h0, wm, am0);
            am1 = fmaf(h1, wm, am1);
            av0 = fmaf(h0, wv, av0);
            av1 = fmaf(h1, wv, av1);
        }
#pragma unroll
        for (int s = 32; s; s >>= 1) {
            am0 += __shfl_xor(am0, s, 64);
            am1 += __shfl_xor(am1, s, 64);
            av0 += __shfl_xor(av0, s, 64);
            av1 += __shfl_xor(av1, s, 64);
        }
        if (l < 2) {
            float am = l ? am1 : am0;
            float av = l ? av1 : av0;
            int b = b0 + l;
            if (o < 48) {
                float umu = tanhf(am + bum[o]);
                // F.threshold(x,-6,-6): max(x,-6)
                float uvar = expf(fmaxf(av + buv[o], -6.f));
                u_out[b * 48 + o] = umu + uvar * eps_u[b * 48 + o];
            } else {
                int n = o - 48;
                float gmu = tanhf(am + bgm[n]);
                float gpre = av + bgv[n];
                // F.threshold(x,-6,6): x>-6 ? x : 6
                float gvar = expf(gpre > -6.f ? gpre : 6.f);
                gu_out[b * 3 + n] = gmu + gvar * eps_g[b * 3 + n];
            }
        }
    }
}

// ---------------------------------------------------------------------------
// Parts: sigmoid of column-sums of Wz [32,4096] -> 16 patches of 16x16.
// (ones(B,ZD) @ Wz makes every batch row identical.)
// ---------------------------------------------------------------------------
__global__ __launch_bounds__(256) void parts_kernel(
    const float* __restrict__ Wz, float* __restrict__ out)
{
    int idx = blockIdx.x * 256 + threadIdx.x;  // 0..4095
    float s = 0.f;
#pragma unroll
    for (int z = 0; z < 32; z++) s += Wz[z * 4096 + idx];
    out[idx] = 1.f / (1.f + expf(-s));
}

// ---------------------------------------------------------------------------
// Composite: for each (b,i,j), loop p=0..15:
//   km = bilinear(M[b*16+p] anchor-shifted, translation u)   [fused int shift]
//   xp = bilinear(part patch at anchor offset, rotation+translation u)
//   num += xp*km; den += km;   x = num / (den==0?1:den)
// grid = (256 batches, 4 row-chunks), 256 threads, 4 pixels/thread.
// ---------------------------------------------------------------------------
__global__ __launch_bounds__(256) void composite_kernel(
    const float* __restrict__ M, const float* __restrict__ parts,
    const float* __restrict__ u, float* __restrict__ xout)
{
    __shared__ float patch[16 * 256];
    __shared__ float pc[16], psn[16], ptx[16], pty[16];
    int b = blockIdx.x;
    int tid = threadIdx.x;
    for (int i = tid; i < 4096; i += 256) patch[i] = parts[i];
    if (tid < 16) {
        const float* up = u + (b * 16 + tid) * 3;
        float ang = up[0];
        pc[tid] = cosf(ang);
        psn[tid] = sinf(ang);
        ptx[tid] = up[1];
        pty[tid] = up[2];
    }
    __syncthreads();

    for (int t = 0; t < 4; t++) {
        int pix = blockIdx.y * 1024 + t * 256 + tid;
        int ii = pix >> 6, jj = pix & 63;
        float xn = (float)(2 * jj + 1) * (1.f / 64.f) - 1.f;
        float yn = (float)(2 * ii + 1) * (1.f / 64.f) - 1.f;
        float num = 0.f, den = 0.f;
#pragma unroll
        for (int p = 0; p < 16; p++) {
            int dx = 8 * (p & 3) - 12;
            int dy = 8 * (p >> 2) - 12;
            float c = pc[p], s = psn[p], tx = ptx[p], ty = pty[p];
            // ---- KM: translation-only sample of anchor-shifted M ----
            float km;
            {
                float gx = xn + tx;
                float gy = yn + ty;
                float xs = (gx + 1.f) * 32.f - 0.5f;
                float ysv = (gy + 1.f) * 32.f - 0.5f;
                float xf = floorf(xs), yf = floorf(ysv);
                float wx = xs - xf, wy = ysv - yf;
                int x0 = (int)xf, y0 = (int)yf;
                const float* Mp = M + ((size_t)(b * 16 + p) << 12);
                int lox = dx < 0 ? -dx : 0;
                int hix = dx > 0 ? 64 - dx : 64;
                int loy = dy < 0 ? -dy : 0;
                int hiy = dy > 0 ? 64 - dy : 64;
                float v00 = 0.f, v10 = 0.f, v01 = 0.f, v11 = 0.f;
                bool vx0 = (x0 >= lox) && (x0 < hix);
                bool vx1 = (x0 + 1 >= lox) && (x0 + 1 < hix);
                if ((y0 >= loy) && (y0 < hiy)) {
                    const float* row = Mp + (y0 + dy) * 64 + dx;
                    if (vx0) v00 = row[x0];
                    if (vx1) v10 = row[x0 + 1];
                }
                if ((y0 + 1 >= loy) && (y0 + 1 < hiy)) {
                    const float* row = Mp + (y0 + 1 + dy) * 64 + dx;
                    if (vx0) v01 = row[x0];
                    if (vx1) v11 = row[x0 + 1];
                }
                km = v00 * (1.f - wx) * (1.f - wy) + v10 * wx * (1.f - wy)
                   + v01 * (1.f - wx) * wy + v11 * wx * wy;
            }
            // ---- xp: rotation+translation sample of anchored part patch ----
            float xp;
            {
                float gx = c * xn - s * yn + tx;
                float gy = s * xn + c * yn + ty;
                float xs = (gx + 1.f) * 32.f - 0.5f;
                float ysv = (gy + 1.f) * 32.f - 0.5f;
                float xf = floorf(xs), yf = floorf(ysv);
                float wx = xs - xf, wy = ysv - yf;
                int x0 = (int)xf, y0 = (int)yf;
                int ox = 24 - dx, oy = 24 - dy;  // patch origin in anchored image
                int a0 = y0 - oy, a1 = a0 + 1;
                int b0 = x0 - ox, b1c = b0 + 1;
                const float* pp = patch + p * 256;
                float v00 = 0.f, v10 = 0.f, v01 = 0.f, v11 = 0.f;
                if ((unsigned)a0 < 16u) {
                    if ((unsigned)b0 < 16u) v00 = pp[a0 * 16 + b0];
                    if ((unsigned)b1c < 16u) v10 = pp[a0 * 16 + b1c];
                }
                if ((unsigned)a1 < 16u) {
                    if ((unsigned)b0 < 16u) v01 = pp[a1 * 16 + b0];
                    if ((unsigned)b1c < 16u) v11 = pp[a1 * 16 + b1c];
                }
                xp = v00 * (1.f - wx) * (1.f - wy) + v10 * wx * (1.f - wy)
                   + v01 * (1.f - wx) * wy + v11 * wx * wy;
            }
            num += xp * km;
            den += km;
        }
        float d = (den == 0.f) ? 1.f : den;
        xout[(size_t)b * 4096 + pix] = num / d;
    }
}

// ---------------------------------------------------------------------------
// Final global transform: out[b] = bilinear(x[b], rot_tr(gu[b]) grid)
// ---------------------------------------------------------------------------
__global__ __launch_bounds__(256) void final_kernel(
    const float* __restrict__ xin, const float* __restrict__ gu,
    float* __restrict__ out)
{
    int id = blockIdx.x * 256 + threadIdx.x;  // 1048576
    int b = id >> 12;
    int pix = id & 4095;
    int ii = pix >> 6, jj = pix & 63;
    float ang = gu[b * 3 + 0], tx = gu[b * 3 + 1], ty = gu[b * 3 + 2];
    float c = cosf(ang), s = sinf(ang);
    float xn = (float)(2 * jj + 1) * (1.f / 64.f) - 1.f;
    float yn = (float)(2 * ii + 1) * (1.f / 64.f) - 1.f;
    float gx = c * xn - s * yn + tx;
    float gy = s * xn + c * yn + ty;
    float xs = (gx + 1.f) * 32.f - 0.5f;
    float ysv = (gy + 1.f) * 32.f - 0.5f;
    float xf = floorf(xs), yf = floorf(ysv);
    float wx = xs - xf, wy = ysv - yf;
    int x0 = (int)xf, y0 = (int)yf;
    const float* xp = xin + ((size_t)b << 12);
    float v00 = 0.f, v10 = 0.f, v01 = 0.f, v11 = 0.f;
    bool vx0 = (unsigned)x0 < 64u, vx1 = (unsigned)(x0 + 1) < 64u;
    if ((unsigned)y0 < 64u) {
        if (vx0) v00 = xp[y0 * 64 + x0];
        if (vx1) v10 = xp[y0 * 64 + x0 + 1];
    }
    if ((unsigned)(y0 + 1) < 64u) {
        if (vx0) v01 = xp[(y0 + 1) * 64 + x0];
        if (vx1) v11 = xp[(y0 + 1) * 64 + x0 + 1];
    }
    out[id] = v00 * (1.f - wx) * (1.f - wy) + v10 * wx * (1.f - wy)
            + v01 * (1.f - wx) * wy + v11 * wx * wy;
}

// ---------------------------------------------------------------------------
extern "C" void kernel_launch(void* const* d_in, const int* in_sizes, int n_in,
                              void* d_out, int out_size, void* d_ws, size_t ws_size,
                              hipStream_t stream)
{
    (void)in_sizes; (void)n_in; (void)out_size; (void)ws_size;
    const float* inputs = (const float*)d_in[0];
    const float* W1  = (const float*)d_in[1];
    const float* b1  = (const float*)d_in[2];
    const float* W2  = (const float*)d_in[3];
    const float* b2  = (const float*)d_in[4];
    const float* Wum = (const float*)d_in[5];
    const float* bum = (const float*)d_in[6];
    const float* Wuv = (const float*)d_in[7];
    const float* buv = (const float*)d_in[8];
    const float* Wgm = (const float*)d_in[9];
    const float* bgm = (const float*)d_in[10];
    const float* Wgv = (const float*)d_in[11];
    const float* bgv = (const float*)d_in[12];
    const float* Wz  = (const float*)d_in[13];
    const float* Mm  = (const float*)d_in[14];
    const float* eps_u = (const float*)d_in[15];
    const float* eps_g = (const float*)d_in[16];

    float* ws = (float*)d_ws;
    float* hid1      = ws;                                   // 262144
    float* hid2      = ws + 262144;                          // 262144
    float* psum      = ws + 524288;                          // SPLITK*262144
    float* u_buf     = ws + 524288 + SPLITK * 262144;        // 12288
    float* gu_buf    = u_buf + 12288;                        // 768
    float* parts_buf = gu_buf + 768;                         // 4096
    float* x_buf     = parts_buf + 4096;                     // 1048576
    float* WT_buf    = x_buf + 1048576;                      // 104448

    // Head-weight transpose (independent of GEMMs)
    transpose_heads<<<408, 256, 0, stream>>>(Wum, Wuv, Wgm, Wgv, WT_buf);
    // Part patches (batch-independent)
    parts_kernel<<<16, 256, 0, stream>>>(Wz, parts_buf);
    // MLP layer 1: [256,4096] @ [4096,1024]
    gemm_splitk<<<dim3(16, 4, SPLITK), 256, 0, stream>>>(inputs, W1, psum, 4096, 4096 / SPLITK);
    reduce_bias_relu<<<1024, 256, 0, stream>>>(psum, b1, hid1);
    // MLP layer 2: [256,1024] @ [1024,1024]
    gemm_splitk<<<dim3(16, 4, SPLITK), 256, 0, stream>>>(hid1, W2, psum, 1024, 1024 / SPLITK);
    reduce_bias_relu<<<1024, 256, 0, stream>>>(psum, b2, hid2);
    // Heads -> u [4096,3], gu [256,3]
    heads_compute<<<128, 512, 0, stream>>>(hid2, WT_buf, bum, buv, bgm, bgv,
                                           eps_u, eps_g, u_buf, gu_buf);
    // Masked compositing -> x [256,64,64]
    composite_kernel<<<dim3(256, 4), 256, 0, stream>>>(Mm, parts_buf, u_buf, x_buf);
    // Global transform -> out [256,1,64,64]
    final_kernel<<<4096, 256, 0, stream>>>(x_buf, gu_buf, (float*)d_out);
}

// Round 3
// 277.156 us; speedup vs baseline: 1.3934x; 1.1921x over previous
//
#include <hip/hip_runtime.h>
#include <math.h>

// Problem constants
// B=256, H=W=64, P=16, PH=PW=16, ZD=32, HD=1024, UD=3, IN=4096
#define SPLITK 8

// ---------------------------------------------------------------------------
// GEMM (fp32, split-K): C_partial[s] = A[256,K_chunk] @ W[K_chunk,1024]
// Block: 64x64 tile, 256 threads, 4x4 micro-tile per thread.
// grid = (N/64=16, M/64=4, SPLITK)
// ---------------------------------------------------------------------------
__global__ __launch_bounds__(256) void gemm_splitk(
    const float* __restrict__ A, const float* __restrict__ W,
    float* __restrict__ psum, int K, int kchunk)
{
    const int N = 1024;
    __shared__ __align__(16) float As[16][64];
    __shared__ __align__(16) float Bs[16][64];
    int tid = threadIdx.x;
    int n0 = blockIdx.x * 64;
    int m0 = blockIdx.y * 64;
    int k_begin = blockIdx.z * kchunk;

    int tx = tid & 15, ty = tid >> 4;
    int am = tid >> 2, ak = (tid & 3) << 2;   // A tile load: row am, 4 k's
    int wk = tid >> 4, wn = (tid & 15) << 2;  // W tile load: k row wk, 4 n's

    float acc[4][4] = {};

    for (int k0 = k_begin; k0 < k_begin + kchunk; k0 += 16) {
        float4 av = *(const float4*)(A + (m0 + am) * K + (k0 + ak));
        float4 wv = *(const float4*)(W + (k0 + wk) * N + (n0 + wn));
        __syncthreads();
        As[ak + 0][am] = av.x;
        As[ak + 1][am] = av.y;
        As[ak + 2][am] = av.z;
        As[ak + 3][am] = av.w;
        *(float4*)&Bs[wk][wn] = wv;
        __syncthreads();
#pragma unroll
        for (int kk = 0; kk < 16; kk++) {
            float4 a4 = *(const float4*)&As[kk][ty << 2];
            float4 b4 = *(const float4*)&Bs[kk][tx << 2];
            acc[0][0] = fmaf(a4.x, b4.x, acc[0][0]);
            acc[0][1] = fmaf(a4.x, b4.y, acc[0][1]);
            acc[0][2] = fmaf(a4.x, b4.z, acc[0][2]);
            acc[0][3] = fmaf(a4.x, b4.w, acc[0][3]);
            acc[1][0] = fmaf(a4.y, b4.x, acc[1][0]);
            acc[1][1] = fmaf(a4.y, b4.y, acc[1][1]);
            acc[1][2] = fmaf(a4.y, b4.z, acc[1][2]);
            acc[1][3] = fmaf(a4.y, b4.w, acc[1][3]);
            acc[2][0] = fmaf(a4.z, b4.x, acc[2][0]);
            acc[2][1] = fmaf(a4.z, b4.y, acc[2][1]);
            acc[2][2] = fmaf(a4.z, b4.z, acc[2][2]);
            acc[2][3] = fmaf(a4.z, b4.w, acc[2][3]);
            acc[3][0] = fmaf(a4.w, b4.x, acc[3][0]);
            acc[3][1] = fmaf(a4.w, b4.y, acc[3][1]);
            acc[3][2] = fmaf(a4.w, b4.z, acc[3][2]);
            acc[3][3] = fmaf(a4.w, b4.w, acc[3][3]);
        }
    }

    float* op = psum + (size_t)blockIdx.z * (256 * 1024);
#pragma unroll
    for (int r = 0; r < 4; r++) {
        float4 v = make_float4(acc[r][0], acc[r][1], acc[r][2], acc[r][3]);
        *(float4*)(op + (m0 + (ty << 2) + r) * N + n0 + (tx << 2)) = v;
    }
}

// ---------------------------------------------------------------------------
// Reduce split-K partials + bias + relu.  total = 256*1024 elements.
// ---------------------------------------------------------------------------
__global__ __launch_bounds__(256) void reduce_bias_relu(
    const float* __restrict__ psum, const float* __restrict__ bias,
    float* __restrict__ out)
{
    int i = blockIdx.x * 256 + threadIdx.x;
    float v = 0.f;
#pragma unroll
    for (int s = 0; s < SPLITK; s++) v += psum[(size_t)s * 262144 + i];
    v += bias[i & 1023];
    out[i] = fmaxf(v, 0.f);
}

// ---------------------------------------------------------------------------
// Transpose head weights into k-major WT[102][1024].
// ---------------------------------------------------------------------------
__global__ __launch_bounds__(256) void transpose_heads(
    const float* __restrict__ Wum, const float* __restrict__ Wuv,
    const float* __restrict__ Wgm, const float* __restrict__ Wgv,
    float* __restrict__ WT)
{
    int id = blockIdx.x * 256 + threadIdx.x;   // 102*1024 = 104448
    int o = id >> 10;
    int k = id & 1023;
    float v;
    if (o < 48)       v = Wum[k * 48 + o];
    else if (o < 96)  v = Wuv[k * 48 + (o - 48)];
    else if (o < 99)  v = Wgm[k * 3 + (o - 96)];
    else              v = Wgv[k * 3 + (o - 99)];
    WT[id] = v;
}

// ---------------------------------------------------------------------------
// Heads: wave-per-output-pair, coalesced k-major weights, shfl reduce.
// ---------------------------------------------------------------------------
__global__ __launch_bounds__(512) void heads_compute(
    const float* __restrict__ hid, const float* __restrict__ WT,
    const float* __restrict__ bum, const float* __restrict__ buv,
    const float* __restrict__ bgm, const float* __restrict__ bgv,
    const float* __restrict__ eps_u, const float* __restrict__ eps_g,
    float* __restrict__ u_out, float* __restrict__ gu_out)
{
    __shared__ float h[2048];
    int b0 = blockIdx.x << 1;
    int tid = threadIdx.x;
    const float* hp = hid + b0 * 1024;
    for (int i = tid; i < 2048; i += 512) h[i] = hp[i];
    __syncthreads();
    int w = tid >> 6, l = tid & 63;
    for (int o = w; o < 51; o += 8) {
        int rm = (o < 48) ? o : (48 + o);        // mu row:  o  or 96+(o-48)
        int rv = (o < 48) ? (o + 48) : (51 + o); // var row: 48+o or 99+(o-48)
        const float* wmp = WT + rm * 1024;
        const float* wvp = WT + rv * 1024;
        float am0 = 0.f, am1 = 0.f, av0 = 0.f, av1 = 0.f;
#pragma unroll
        for (int j0 = 0; j0 < 1024; j0 += 64) {
            int j = j0 + l;
            float wm = wmp[j], wv = wvp[j];
            float h0 = h[j], h1 = h[1024 + j];
            am0 = fmaf(h0, wm, am0);
            am1 = fmaf(h1, wm, am1);
            av0 = fmaf(h0, wv, av0);
            av1 = fmaf(h1, wv, av1);
        }
#pragma unroll
        for (int s = 32; s; s >>= 1) {
            am0 += __shfl_xor(am0, s, 64);
            am1 += __shfl_xor(am1, s, 64);
            av0 += __shfl_xor(av0, s, 64);
            av1 += __shfl_xor(av1, s, 64);
        }
        if (l < 2) {
            float am = l ? am1 : am0;
            float av = l ? av1 : av0;
            int b = b0 + l;
            if (o < 48) {
                float umu = tanhf(am + bum[o]);
                float uvar = expf(fmaxf(av + buv[o], -6.f));  // threshold(-6,-6)
                u_out[b * 48 + o] = umu + uvar * eps_u[b * 48 + o];
            } else {
                int n = o - 48;
                float gmu = tanhf(am + bgm[n]);
                float gpre = av + bgv[n];
                float gvar = expf(gpre > -6.f ? gpre : 6.f);  // threshold(-6,6)
                gu_out[b * 3 + n] = gmu + gvar * eps_g[b * 3 + n];
            }
        }
    }
}

// ---------------------------------------------------------------------------
// Parts: sigmoid of column-sums of Wz [32,4096] -> 16 patches of 16x16.
// ---------------------------------------------------------------------------
__global__ __launch_bounds__(256) void parts_kernel(
    const float* __restrict__ Wz, float* __restrict__ out)
{
    int idx = blockIdx.x * 256 + threadIdx.x;  // 0..4095
    float s = 0.f;
#pragma unroll
    for (int z = 0; z < 32; z++) s += Wz[z * 4096 + idx];
    out[idx] = 1.f / (1.f + expf(-s));
}

// ---------------------------------------------------------------------------
// Composite v2: LDS-staged M planes, separable translation for km.
// grid = 512 blocks = (batch b = blk>>1, row-half = blk&1), 256 threads.
// Thread: column j = tid&63, rows i0..i0+7 (i0 = half*32 + (tid>>6)*8).
// Loop p: stage M plane (register-prefetch pipelined), compute km
// (fixed 2x2 weights, shared column-blend R) and xp (rotated patch sample
// from LDS, execz-skipped where outside), accumulate num/den in regs.
// ---------------------------------------------------------------------------
__global__ __launch_bounds__(256) void composite_v2(
    const float* __restrict__ M, const float* __restrict__ parts,
    const float* __restrict__ u, float* __restrict__ xout)
{
    __shared__ float patch[4096];
    __shared__ float plane[4096];
    __shared__ float pc[16], psn[16], ptx[16], pty[16];
    int b = blockIdx.x >> 1;
    int half = blockIdx.x & 1;
    int tid = threadIdx.x;

    for (int i = tid; i < 4096; i += 256) patch[i] = parts[i];
    if (tid < 16) {
        const float* up = u + (b * 16 + tid) * 3;
        float ang = up[0];
        pc[tid] = cosf(ang);
        psn[tid] = sinf(ang);
        ptx[tid] = up[1];
        pty[tid] = up[2];
    }

    int j = tid & 63;
    int i0 = half * 32 + (tid >> 6) * 8;
    float xnv = (float)(2 * j + 1) * (1.f / 64.f) - 1.f;

    float num[8] = {}, den[8] = {};

    // prefetch plane 0
    const float* Mb = M + ((size_t)(b * 16) << 12);
    float4 pf0, pf1, pf2, pf3;
    {
        const float4* src = (const float4*)Mb;
        pf0 = src[tid];
        pf1 = src[tid + 256];
        pf2 = src[tid + 512];
        pf3 = src[tid + 768];
    }
    __syncthreads();   // patch + params visible

    for (int p = 0; p < 16; p++) {
        {
            float4* dst = (float4*)plane;
            dst[tid] = pf0;
            dst[tid + 256] = pf1;
            dst[tid + 512] = pf2;
            dst[tid + 768] = pf3;
        }
        __syncthreads();
        if (p < 15) {
            const float4* src = (const float4*)(Mb + ((size_t)(p + 1) << 12));
            pf0 = src[tid];
            pf1 = src[tid + 256];
            pf2 = src[tid + 512];
            pf3 = src[tid + 768];
        }
        int dx = 8 * (p & 3) - 12;
        int dy = 8 * (p >> 2) - 12;
        float c = pc[p], s = psn[p], tx = ptx[p], ty = pty[p];

        // ---- km: translation decomposition (weights constant per (b,p)) ----
        float ax = fminf(fmaxf(32.f * tx, -16384.f), 16384.f);
        float fax = floorf(ax);
        float wx = ax - fax;
        int ix = (int)fax;
        float ay = fminf(fmaxf(32.f * ty, -16384.f), 16384.f);
        float fay = floorf(ay);
        float wy = ay - fay;
        int iy = (int)fay;

        int x0 = j + ix;           // image col of corner 0
        int X = x0 + dx;           // source plane col
        bool vc0 = ((unsigned)x0 < 64u) && ((unsigned)X < 64u);
        bool vc1 = ((unsigned)(x0 + 1) < 64u) && ((unsigned)(X + 1) < 64u);
        float w0 = vc0 ? (1.f - wx) : 0.f;
        float w1 = vc1 ? wx : 0.f;
        int Xc0 = min(max(X, 0), 63);
        int Xc1 = min(max(X + 1, 0), 63);
        int iY = iy + dy;

        float R[9];
#pragma unroll
        for (int r = 0; r < 9; r++) {
            int i = i0 + r;
            int y0i = i + iy;      // image row of corner
            int ri = i + iY;       // source plane row
            bool vr = ((unsigned)y0i < 64u) && ((unsigned)ri < 64u);
            int ric = min(max(ri, 0), 63);
            const float* row = plane + (ric << 6);
            float val = fmaf(w0, row[Xc0], w1 * row[Xc1]);
            R[r] = vr ? val : 0.f;
        }

        // ---- xp: rotated sample of 16x16 patch ----
        float Ax = fmaf(c, xnv, tx);   // c*xn + tx
        float Ay = fmaf(s, xnv, ty);   // s*xn + ty
        int ox = 24 - dx, oy = 24 - dy;
        const float* pp = patch + (p << 8);
#pragma unroll
        for (int r = 0; r < 8; r++) {
            int i = i0 + r;
            float km = fmaf(wy, R[r + 1] - R[r], R[r]);
            den[r] += km;

            float ynv = (float)(2 * i + 1) * (1.f / 64.f) - 1.f;
            float gx = fmaf(-s, ynv, Ax);
            float gy = fmaf(c, ynv, Ay);
            gx = fminf(fmaxf(gx, -8.f), 8.f);
            gy = fminf(fmaxf(gy, -8.f), 8.f);
            float xs = fmaf(gx, 32.f, 31.5f);
            float ysv = fmaf(gy, 32.f, 31.5f);
            float xf = floorf(xs), yf = floorf(ysv);
            float wxx = xs - xf, wyy = ysv - yf;
            int a0 = (int)yf - oy;
            int b0c = (int)xf - ox;
            if ((unsigned)(a0 + 1) <= 16u && (unsigned)(b0c + 1) <= 16u) {
                float v00 = 0.f, v10 = 0.f, v01 = 0.f, v11 = 0.f;
                if ((unsigned)a0 < 16u) {
                    const float* pr = pp + a0 * 16;
                    if ((unsigned)b0c < 16u) v00 = pr[b0c];
                    if ((unsigned)(b0c + 1) < 16u) v10 = pr[b0c + 1];
                }
                if ((unsigned)(a0 + 1) < 16u) {
                    const float* pr = pp + (a0 + 1) * 16;
                    if ((unsigned)b0c < 16u) v01 = pr[b0c];
                    if ((unsigned)(b0c + 1) < 16u) v11 = pr[b0c + 1];
                }
                float top = fmaf(wxx, v10 - v00, v00);
                float bot = fmaf(wxx, v11 - v01, v01);
                float xp = fmaf(wyy, bot - top, top);
                num[r] = fmaf(xp, km, num[r]);
            }
        }
        __syncthreads();
    }

    float* xo = xout + ((size_t)b << 12);
#pragma unroll
    for (int r = 0; r < 8; r++) {
        float d = (den[r] == 0.f) ? 1.f : den[r];
        xo[(i0 + r) * 64 + j] = num[r] / d;
    }
}

// ---------------------------------------------------------------------------
// Final global transform: out[b] = bilinear(x[b], rot_tr(gu[b]) grid)
// ---------------------------------------------------------------------------
__global__ __launch_bounds__(256) void final_kernel(
    const float* __restrict__ xin, const float* __restrict__ gu,
    float* __restrict__ out)
{
    int id = blockIdx.x * 256 + threadIdx.x;  // 1048576
    int b = id >> 12;
    int pix = id & 4095;
    int ii = pix >> 6, jj = pix & 63;
    float ang = gu[b * 3 + 0], tx = gu[b * 3 + 1], ty = gu[b * 3 + 2];
    float c = cosf(ang), s = sinf(ang);
    float xn = (float)(2 * jj + 1) * (1.f / 64.f) - 1.f;
    float yn = (float)(2 * ii + 1) * (1.f / 64.f) - 1.f;
    float gx = c * xn - s * yn + tx;
    float gy = s * xn + c * yn + ty;
    float xs = (gx + 1.f) * 32.f - 0.5f;
    float ysv = (gy + 1.f) * 32.f - 0.5f;
    float xf = floorf(xs), yf = floorf(ysv);
    float wx = xs - xf, wy = ysv - yf;
    int x0 = (int)xf, y0 = (int)yf;
    const float* xp = xin + ((size_t)b << 12);
    float v00 = 0.f, v10 = 0.f, v01 = 0.f, v11 = 0.f;
    bool vx0 = (unsigned)x0 < 64u, vx1 = (unsigned)(x0 + 1) < 64u;
    if ((unsigned)y0 < 64u) {
        if (vx0) v00 = xp[y0 * 64 + x0];
        if (vx1) v10 = xp[y0 * 64 + x0 + 1];
    }
    if ((unsigned)(y0 + 1) < 64u) {
        if (vx0) v01 = xp[(y0 + 1) * 64 + x0];
        if (vx1) v11 = xp[(y0 + 1) * 64 + x0 + 1];
    }
    out[id] = v00 * (1.f - wx) * (1.f - wy) + v10 * wx * (1.f - wy)
            + v01 * (1.f - wx) * wy + v11 * wx * wy;
}

// ---------------------------------------------------------------------------
extern "C" void kernel_launch(void* const* d_in, const int* in_sizes, int n_in,
                              void* d_out, int out_size, void* d_ws, size_t ws_size,
                              hipStream_t stream)
{
    (void)in_sizes; (void)n_in; (void)out_size; (void)ws_size;
    const float* inputs = (const float*)d_in[0];
    const float* W1  = (const float*)d_in[1];
    const float* b1  = (const float*)d_in[2];
    const float* W2  = (const float*)d_in[3];
    const float* b2  = (const float*)d_in[4];
    const float* Wum = (const float*)d_in[5];
    const float* bum = (const float*)d_in[6];
    const float* Wuv = (const float*)d_in[7];
    const float* buv = (const float*)d_in[8];
    const float* Wgm = (const float*)d_in[9];
    const float* bgm = (const float*)d_in[10];
    const float* Wgv = (const float*)d_in[11];
    const float* bgv = (const float*)d_in[12];
    const float* Wz  = (const float*)d_in[13];
    const float* Mm  = (const float*)d_in[14];
    const float* eps_u = (const float*)d_in[15];
    const float* eps_g = (const float*)d_in[16];

    float* ws = (float*)d_ws;
    float* hid1      = ws;                                   // 262144
    float* hid2      = ws + 262144;                          // 262144
    float* psum      = ws + 524288;                          // SPLITK*262144
    float* u_buf     = ws + 524288 + SPLITK * 262144;        // 12288
    float* gu_buf    = u_buf + 12288;                        // 768
    float* parts_buf = gu_buf + 768;                         // 4096
    float* x_buf     = parts_buf + 4096;                     // 1048576
    float* WT_buf    = x_buf + 1048576;                      // 104448

    transpose_heads<<<408, 256, 0, stream>>>(Wum, Wuv, Wgm, Wgv, WT_buf);
    parts_kernel<<<16, 256, 0, stream>>>(Wz, parts_buf);
    // MLP layer 1: [256,4096] @ [4096,1024]
    gemm_splitk<<<dim3(16, 4, SPLITK), 256, 0, stream>>>(inputs, W1, psum, 4096, 4096 / SPLITK);
    reduce_bias_relu<<<1024, 256, 0, stream>>>(psum, b1, hid1);
    // MLP layer 2: [256,1024] @ [1024,1024]
    gemm_splitk<<<dim3(16, 4, SPLITK), 256, 0, stream>>>(hid1, W2, psum, 1024, 1024 / SPLITK);
    reduce_bias_relu<<<1024, 256, 0, stream>>>(psum, b2, hid2);
    // Heads -> u [4096,3] (as [256,48]), gu [256,3]
    heads_compute<<<128, 512, 0, stream>>>(hid2, WT_buf, bum, buv, bgm, bgv,
                                           eps_u, eps_g, u_buf, gu_buf);
    // Masked compositing -> x [256,64,64]
    composite_v2<<<512, 256, 0, stream>>>(Mm, parts_buf, u_buf, x_buf);
    // Global transform -> out [256,1,64,64]
    final_kernel<<<4096, 256, 0, stream>>>(x_buf, gu_buf, (float*)d_out);
}

// Round 4
// 259.206 us; speedup vs baseline: 1.4899x; 1.0693x over previous
//
#include <hip/hip_runtime.h>
#include <math.h>

// Problem constants: B=256, H=W=64, P=16, PH=PW=16, ZD=32, HD=1024, UD=3, IN=4096
#define SPLITK 8

typedef __bf16 bf16x8 __attribute__((ext_vector_type(8)));
typedef float  f32x4  __attribute__((ext_vector_type(4)));
typedef short  short8 __attribute__((ext_vector_type(8)));

__device__ inline unsigned short bf16rne(float x) {
    unsigned int u = __float_as_uint(x);
    unsigned int r = u + 0x7FFFu + ((u >> 16) & 1u);
    return (unsigned short)(r >> 16);
}
__device__ inline float bf16tof(unsigned short h) {
    return __uint_as_float(((unsigned int)h) << 16);
}

// ---------------------------------------------------------------------------
// convert_A: fp32 [rows,K] -> Ahi/Alo bf16 (same layout). Elementwise split.
// ---------------------------------------------------------------------------
__global__ __launch_bounds__(256) void convert_a(
    const float* __restrict__ A, unsigned short* __restrict__ hi,
    unsigned short* __restrict__ lo)
{
    int id = blockIdx.x * 256 + threadIdx.x;
    float x = A[id];
    unsigned short h = bf16rne(x);
    unsigned short l = bf16rne(x - bf16tof(h));
    hi[id] = h;
    lo[id] = l;
}

// ---------------------------------------------------------------------------
// convert_wt: W [K,1024] -> WT{hi,lo} [1024,K] (transposed, k-contiguous),
// split into bf16 hi/lo.  grid = (1024/32, K/32), 256 threads, LDS 32x33 tile.
// ---------------------------------------------------------------------------
__global__ __launch_bounds__(256) void convert_wt(
    const float* __restrict__ W, unsigned short* __restrict__ Thi,
    unsigned short* __restrict__ Tlo, int K)
{
    __shared__ float t[32][33];
    int n0 = blockIdx.x * 32, k0 = blockIdx.y * 32;
    int tid = threadIdx.x;
    int c = tid & 31, r0 = tid >> 5;
#pragma unroll
    for (int i = 0; i < 4; i++)
        t[r0 + 8 * i][c] = W[(size_t)(k0 + r0 + 8 * i) * 1024 + n0 + c];
    __syncthreads();
    int kk = tid & 31, n1 = tid >> 5;
#pragma unroll
    for (int i = 0; i < 4; i++) {
        float x = t[kk][n1 + 8 * i];
        unsigned short h = bf16rne(x);
        unsigned short l = bf16rne(x - bf16tof(h));
        size_t o = (size_t)(n0 + n1 + 8 * i) * K + k0 + kk;
        Thi[o] = h;
        Tlo[o] = l;
    }
}

// ---------------------------------------------------------------------------
// GEMM bf16x3 (fp32-accurate): psum[z] += A[256,Kc] @ W^T-tiles.
// C = Ahi*Bhi + Ahi*Blo + Alo*Bhi, MFMA 16x16x32_bf16.
// Block: 64x64 tile, 256 thr = 4 waves (2x2), each wave 32x32 (2x2 frags).
// LDS: 4 tiles 64x64 bf16, XOR-swizzled chunks (16B) for conflict-free b128.
// grid = (N/64=16, M/64=4, SPLITK).  kchunk % 64 == 0.
// ---------------------------------------------------------------------------
__global__ __launch_bounds__(256) void gemm_bf16x3(
    const unsigned short* __restrict__ Ahi, const unsigned short* __restrict__ Alo,
    const unsigned short* __restrict__ Bhi, const unsigned short* __restrict__ Blo,
    float* __restrict__ psum, int K, int kchunk)
{
    __shared__ unsigned short Ah[4096], Al[4096], Bh[4096], Bl[4096];
    int tid = threadIdx.x;
    int n0 = blockIdx.x * 64, m0 = blockIdx.y * 64;
    int kb = blockIdx.z * kchunk;
    int wid = tid >> 6, lane = tid & 63;
    int wm = wid & 1, wn = wid >> 1;
    int lm = lane & 15, q = lane >> 4;

    // staging: chunk ids tid and tid+256; row = id>>3, ch = id&7 (16B chunks)
    int r0 = tid >> 3, ch0 = tid & 7;
    int r1 = (tid + 256) >> 3, ch1 = (tid + 256) & 7;
    int l0 = r0 * 64 + 8 * (ch0 ^ (r0 & 7));
    int l1 = r1 * 64 + 8 * (ch1 ^ (r1 & 7));
    size_t ga0 = (size_t)(m0 + r0) * K + kb + ch0 * 8;
    size_t ga1 = (size_t)(m0 + r1) * K + kb + ch1 * 8;
    size_t gb0 = (size_t)(n0 + r0) * K + kb + ch0 * 8;
    size_t gb1 = (size_t)(n0 + r1) * K + kb + ch1 * 8;

    f32x4 acc[2][2] = {};

    int nkt = kchunk >> 6;
    uint4 vah0, vah1, val0, val1, vbh0, vbh1, vbl0, vbl1;
    // prefetch k-tile 0
    vah0 = *(const uint4*)(Ahi + ga0);
    vah1 = *(const uint4*)(Ahi + ga1);
    val0 = *(const uint4*)(Alo + ga0);
    val1 = *(const uint4*)(Alo + ga1);
    vbh0 = *(const uint4*)(Bhi + gb0);
    vbh1 = *(const uint4*)(Bhi + gb1);
    vbl0 = *(const uint4*)(Blo + gb0);
    vbl1 = *(const uint4*)(Blo + gb1);

    // fragment read offsets (halfwords): row m/n in tile, swizzled chunk
    int frm0 = (wm * 32 + lm) * 64;        // mt=0
    int frm1 = (wm * 32 + 16 + lm) * 64;   // mt=1
    int frn0 = (wn * 32 + lm) * 64;
    int frn1 = (wn * 32 + 16 + lm) * 64;
    int sw = lm & 7;

    for (int kt = 0; kt < nkt; kt++) {
        __syncthreads();
        *(uint4*)(Ah + l0) = vah0;
        *(uint4*)(Ah + l1) = vah1;
        *(uint4*)(Al + l0) = val0;
        *(uint4*)(Al + l1) = val1;
        *(uint4*)(Bh + l0) = vbh0;
        *(uint4*)(Bh + l1) = vbh1;
        *(uint4*)(Bl + l0) = vbl0;
        *(uint4*)(Bl + l1) = vbl1;
        __syncthreads();
        if (kt + 1 < nkt) {
            size_t o = (size_t)(kt + 1) * 64;
            vah0 = *(const uint4*)(Ahi + ga0 + o);
            vah1 = *(const uint4*)(Ahi + ga1 + o);
            val0 = *(const uint4*)(Alo + ga0 + o);
            val1 = *(const uint4*)(Alo + ga1 + o);
            vbh0 = *(const uint4*)(Bhi + gb0 + o);
            vbh1 = *(const uint4*)(Bhi + gb1 + o);
            vbl0 = *(const uint4*)(Blo + gb0 + o);
            vbl1 = *(const uint4*)(Blo + gb1 + o);
        }
#pragma unroll
        for (int ks = 0; ks < 2; ks++) {
            int cidx = 8 * (((ks << 2) + q) ^ sw);
            bf16x8 ah0 = *(const bf16x8*)(Ah + frm0 + cidx);
            bf16x8 ah1 = *(const bf16x8*)(Ah + frm1 + cidx);
            bf16x8 al0 = *(const bf16x8*)(Al + frm0 + cidx);
            bf16x8 al1 = *(const bf16x8*)(Al + frm1 + cidx);
            bf16x8 bh0 = *(const bf16x8*)(Bh + frn0 + cidx);
            bf16x8 bh1 = *(const bf16x8*)(Bh + frn1 + cidx);
            bf16x8 bl0 = *(const bf16x8*)(Bl + frn0 + cidx);
            bf16x8 bl1 = *(const bf16x8*)(Bl + frn1 + cidx);
            acc[0][0] = __builtin_amdgcn_mfma_f32_16x16x32_bf16(ah0, bh0, acc[0][0], 0, 0, 0);
            acc[0][0] = __builtin_amdgcn_mfma_f32_16x16x32_bf16(ah0, bl0, acc[0][0], 0, 0, 0);
            acc[0][0] = __builtin_amdgcn_mfma_f32_16x16x32_bf16(al0, bh0, acc[0][0], 0, 0, 0);
            acc[0][1] = __builtin_amdgcn_mfma_f32_16x16x32_bf16(ah0, bh1, acc[0][1], 0, 0, 0);
            acc[0][1] = __builtin_amdgcn_mfma_f32_16x16x32_bf16(ah0, bl1, acc[0][1], 0, 0, 0);
            acc[0][1] = __builtin_amdgcn_mfma_f32_16x16x32_bf16(al0, bh1, acc[0][1], 0, 0, 0);
            acc[1][0] = __builtin_amdgcn_mfma_f32_16x16x32_bf16(ah1, bh0, acc[1][0], 0, 0, 0);
            acc[1][0] = __builtin_amdgcn_mfma_f32_16x16x32_bf16(ah1, bl0, acc[1][0], 0, 0, 0);
            acc[1][0] = __builtin_amdgcn_mfma_f32_16x16x32_bf16(al1, bh0, acc[1][0], 0, 0, 0);
            acc[1][1] = __builtin_amdgcn_mfma_f32_16x16x32_bf16(ah1, bh1, acc[1][1], 0, 0, 0);
            acc[1][1] = __builtin_amdgcn_mfma_f32_16x16x32_bf16(ah1, bl1, acc[1][1], 0, 0, 0);
            acc[1][1] = __builtin_amdgcn_mfma_f32_16x16x32_bf16(al1, bh1, acc[1][1], 0, 0, 0);
        }
    }

    // Epilogue: C/D layout col = lane&15, row = q*4 + reg  [m89/m91 verified]
    float* op = psum + (size_t)blockIdx.z * (256 * 1024);
#pragma unroll
    for (int mt = 0; mt < 2; mt++)
#pragma unroll
        for (int nt = 0; nt < 2; nt++) {
            int row = m0 + wm * 32 + mt * 16 + q * 4;
            int col = n0 + wn * 32 + nt * 16 + lm;
#pragma unroll
            for (int r = 0; r < 4; r++)
                op[(size_t)(row + r) * 1024 + col] = acc[mt][nt][r];
        }
}

// ---------------------------------------------------------------------------
// Reduce split-K partials + bias + relu -> fp32 out.
// ---------------------------------------------------------------------------
__global__ __launch_bounds__(256) void reduce_bias_relu(
    const float* __restrict__ psum, const float* __restrict__ bias,
    float* __restrict__ out)
{
    int i = blockIdx.x * 256 + threadIdx.x;
    float v = 0.f;
#pragma unroll
    for (int s = 0; s < SPLITK; s++) v += psum[(size_t)s * 262144 + i];
    v += bias[i & 1023];
    out[i] = fmaxf(v, 0.f);
}

// Same, but also emit bf16 hi/lo split (for feeding layer-2 GEMM).
__global__ __launch_bounds__(256) void reduce_bias_relu_split(
    const float* __restrict__ psum, const float* __restrict__ bias,
    unsigned short* __restrict__ hi, unsigned short* __restrict__ lo)
{
    int i = blockIdx.x * 256 + threadIdx.x;
    float v = 0.f;
#pragma unroll
    for (int s = 0; s < SPLITK; s++) v += psum[(size_t)s * 262144 + i];
    v += bias[i & 1023];
    v = fmaxf(v, 0.f);
    unsigned short h = bf16rne(v);
    hi[i] = h;
    lo[i] = bf16rne(v - bf16tof(h));
}

// ---------------------------------------------------------------------------
// Transpose head weights into k-major WT[102][1024].
// ---------------------------------------------------------------------------
__global__ __launch_bounds__(256) void transpose_heads(
    const float* __restrict__ Wum, const float* __restrict__ Wuv,
    const float* __restrict__ Wgm, const float* __restrict__ Wgv,
    float* __restrict__ WT)
{
    int id = blockIdx.x * 256 + threadIdx.x;   // 102*1024 = 104448
    int o = id >> 10;
    int k = id & 1023;
    float v;
    if (o < 48)       v = Wum[k * 48 + o];
    else if (o < 96)  v = Wuv[k * 48 + (o - 48)];
    else if (o < 99)  v = Wgm[k * 3 + (o - 96)];
    else              v = Wgv[k * 3 + (o - 99)];
    WT[id] = v;
}

// ---------------------------------------------------------------------------
// Heads: wave-per-output-pair, coalesced k-major weights, shfl reduce.
// ---------------------------------------------------------------------------
__global__ __launch_bounds__(512) void heads_compute(
    const float* __restrict__ hid, const float* __restrict__ WT,
    const float* __restrict__ bum, const float* __restrict__ buv,
    const float* __restrict__ bgm, const float* __restrict__ bgv,
    const float* __restrict__ eps_u, const float* __restrict__ eps_g,
    float* __restrict__ u_out, float* __restrict__ gu_out)
{
    __shared__ float h[2048];
    int b0 = blockIdx.x << 1;
    int tid = threadIdx.x;
    const float* hp = hid + b0 * 1024;
    for (int i = tid; i < 2048; i += 512) h[i] = hp[i];
    __syncthreads();
    int w = tid >> 6, l = tid & 63;
    for (int o = w; o < 51; o += 8) {
        int rm = (o < 48) ? o : (48 + o);
        int rv = (o < 48) ? (o + 48) : (51 + o);
        const float* wmp = WT + rm * 1024;
        const float* wvp = WT + rv * 1024;
        float am0 = 0.f, am1 = 0.f, av0 = 0.f, av1 = 0.f;
#pragma unroll
        for (int j0 = 0; j0 < 1024; j0 += 64) {
            int j = j0 + l;
            float wm = wmp[j], wv = wvp[j];
            float h0 = h[j], h1 = h[1024 + j];
            am0 = fmaf(h0, wm, am0);
            am1 = fmaf(h1, wm, am1);
            av0 = fmaf(h0, wv, av0);
            av1 = fmaf(h1, wv, av1);
        }
#pragma unroll
        for (int s = 32; s; s >>= 1) {
            am0 += __shfl_xor(am0, s, 64);
            am1 += __shfl_xor(am1, s, 64);
            av0 += __shfl_xor(av0, s, 64);
            av1 += __shfl_xor(av1, s, 64);
        }
        if (l < 2) {
            float am = l ? am1 : am0;
            float av = l ? av1 : av0;
            int b = b0 + l;
            if (o < 48) {
                float umu = tanhf(am + bum[o]);
                float uvar = expf(fmaxf(av + buv[o], -6.f));  // threshold(-6,-6)
                u_out[b * 48 + o] = umu + uvar * eps_u[b * 48 + o];
            } else {
                int n = o - 48;
                float gmu = tanhf(am + bgm[n]);
                float gpre = av + bgv[n];
                float gvar = expf(gpre > -6.f ? gpre : 6.f);  // threshold(-6,6)
                gu_out[b * 3 + n] = gmu + gvar * eps_g[b * 3 + n];
            }
        }
    }
}

// ---------------------------------------------------------------------------
// Parts: sigmoid of column-sums of Wz [32,4096] -> 16 patches of 16x16.
// ---------------------------------------------------------------------------
__global__ __launch_bounds__(256) void parts_kernel(
    const float* __restrict__ Wz, float* __restrict__ out)
{
    int idx = blockIdx.x * 256 + threadIdx.x;
    float s = 0.f;
#pragma unroll
    for (int z = 0; z < 32; z++) s += Wz[z * 4096 + idx];
    out[idx] = 1.f / (1.f + expf(-s));
}

// ---------------------------------------------------------------------------
// Composite v3: like v2 but 1024 blocks (quarter-rows, 4 rows/thread) for
// 2x the resident waves/CU.
// ---------------------------------------------------------------------------
__global__ __launch_bounds__(256) void composite_v3(
    const float* __restrict__ M, const float* __restrict__ parts,
    const float* __restrict__ u, float* __restrict__ xout)
{
    __shared__ float patch[4096];
    __shared__ float plane[4096];
    __shared__ float pc[16], psn[16], ptx[16], pty[16];
    int b = blockIdx.x >> 2;
    int quarter = blockIdx.x & 3;
    int tid = threadIdx.x;

    for (int i = tid; i < 4096; i += 256) patch[i] = parts[i];
    if (tid < 16) {
        const float* up = u + (b * 16 + tid) * 3;
        float ang = up[0];
        pc[tid] = cosf(ang);
        psn[tid] = sinf(ang);
        ptx[tid] = up[1];
        pty[tid] = up[2];
    }

    int j = tid & 63;
    int i0 = quarter * 16 + (tid >> 6) * 4;
    float xnv = (float)(2 * j + 1) * (1.f / 64.f) - 1.f;

    float num[4] = {}, den[4] = {};

    const float* Mb = M + ((size_t)(b * 16) << 12);
    float4 pf0, pf1, pf2, pf3;
    {
        const float4* src = (const float4*)Mb;
        pf0 = src[tid];
        pf1 = src[tid + 256];
        pf2 = src[tid + 512];
        pf3 = src[tid + 768];
    }
    __syncthreads();

    for (int p = 0; p < 16; p++) {
        {
            float4* dst = (float4*)plane;
            dst[tid] = pf0;
            dst[tid + 256] = pf1;
            dst[tid + 512] = pf2;
            dst[tid + 768] = pf3;
        }
        __syncthreads();
        if (p < 15) {
            const float4* src = (const float4*)(Mb + ((size_t)(p + 1) << 12));
            pf0 = src[tid];
            pf1 = src[tid + 256];
            pf2 = src[tid + 512];
            pf3 = src[tid + 768];
        }
        int dx = 8 * (p & 3) - 12;
        int dy = 8 * (p >> 2) - 12;
        float c = pc[p], s = psn[p], tx = ptx[p], ty = pty[p];

        // km: translation decomposition (weights constant per (b,p))
        float ax = fminf(fmaxf(32.f * tx, -16384.f), 16384.f);
        float fax = floorf(ax);
        float wx = ax - fax;
        int ix = (int)fax;
        float ay = fminf(fmaxf(32.f * ty, -16384.f), 16384.f);
        float fay = floorf(ay);
        float wy = ay - fay;
        int iy = (int)fay;

        int x0 = j + ix;
        int X = x0 + dx;
        bool vc0 = ((unsigned)x0 < 64u) && ((unsigned)X < 64u);
        bool vc1 = ((unsigned)(x0 + 1) < 64u) && ((unsigned)(X + 1) < 64u);
        float w0 = vc0 ? (1.f - wx) : 0.f;
        float w1 = vc1 ? wx : 0.f;
        int Xc0 = min(max(X, 0), 63);
        int Xc1 = min(max(X + 1, 0), 63);
        int iY = iy + dy;

        float R[5];
#pragma unroll
        for (int r = 0; r < 5; r++) {
            int i = i0 + r;
            int y0i = i + iy;
            int ri = i + iY;
            bool vr = ((unsigned)y0i < 64u) && ((unsigned)ri < 64u);
            int ric = min(max(ri, 0), 63);
            const float* row = plane + (ric << 6);
            float val = fmaf(w0, row[Xc0], w1 * row[Xc1]);
            R[r] = vr ? val : 0.f;
        }

        // xp: rotated sample of 16x16 patch
        float Ax = fmaf(c, xnv, tx);
        float Ay = fmaf(s, xnv, ty);
        int ox = 24 - dx, oy = 24 - dy;
        const float* pp = patch + (p << 8);
#pragma unroll
        for (int r = 0; r < 4; r++) {
            int i = i0 + r;
            float km = fmaf(wy, R[r + 1] - R[r], R[r]);
            den[r] += km;

            float ynv = (float)(2 * i + 1) * (1.f / 64.f) - 1.f;
            float gx = fmaf(-s, ynv, Ax);
            float gy = fmaf(c, ynv, Ay);
            gx = fminf(fmaxf(gx, -8.f), 8.f);
            gy = fminf(fmaxf(gy, -8.f), 8.f);
            float xs = fmaf(gx, 32.f, 31.5f);
            float ysv = fmaf(gy, 32.f, 31.5f);
            float xf = floorf(xs), yf = floorf(ysv);
            float wxx = xs - xf, wyy = ysv - yf;
            int a0 = (int)yf - oy;
            int b0c = (int)xf - ox;
            if ((unsigned)(a0 + 1) <= 16u && (unsigned)(b0c + 1) <= 16u) {
                float v00 = 0.f, v10 = 0.f, v01 = 0.f, v11 = 0.f;
                if ((unsigned)a0 < 16u) {
                    const float* pr = pp + a0 * 16;
                    if ((unsigned)b0c < 16u) v00 = pr[b0c];
                    if ((unsigned)(b0c + 1) < 16u) v10 = pr[b0c + 1];
                }
                if ((unsigned)(a0 + 1) < 16u) {
                    const float* pr = pp + (a0 + 1) * 16;
                    if ((unsigned)b0c < 16u) v01 = pr[b0c];
                    if ((unsigned)(b0c + 1) < 16u) v11 = pr[b0c + 1];
                }
                float top = fmaf(wxx, v10 - v00, v00);
                float bot = fmaf(wxx, v11 - v01, v01);
                float xp = fmaf(wyy, bot - top, top);
                num[r] = fmaf(xp, km, num[r]);
            }
        }
        __syncthreads();
    }

    float* xo = xout + ((size_t)b << 12);
#pragma unroll
    for (int r = 0; r < 4; r++) {
        float d = (den[r] == 0.f) ? 1.f : den[r];
        xo[(i0 + r) * 64 + j] = num[r] / d;
    }
}

// ---------------------------------------------------------------------------
// Final global transform: out[b] = bilinear(x[b], rot_tr(gu[b]) grid)
// ---------------------------------------------------------------------------
__global__ __launch_bounds__(256) void final_kernel(
    const float* __restrict__ xin, const float* __restrict__ gu,
    float* __restrict__ out)
{
    int id = blockIdx.x * 256 + threadIdx.x;  // 1048576
    int b = id >> 12;
    int pix = id & 4095;
    int ii = pix >> 6, jj = pix & 63;
    float ang = gu[b * 3 + 0], tx = gu[b * 3 + 1], ty = gu[b * 3 + 2];
    float c = cosf(ang), s = sinf(ang);
    float xn = (float)(2 * jj + 1) * (1.f / 64.f) - 1.f;
    float yn = (float)(2 * ii + 1) * (1.f / 64.f) - 1.f;
    float gx = c * xn - s * yn + tx;
    float gy = s * xn + c * yn + ty;
    float xs = (gx + 1.f) * 32.f - 0.5f;
    float ysv = (gy + 1.f) * 32.f - 0.5f;
    float xf = floorf(xs), yf = floorf(ysv);
    float wx = xs - xf, wy = ysv - yf;
    int x0 = (int)xf, y0 = (int)yf;
    const float* xp = xin + ((size_t)b << 12);
    float v00 = 0.f, v10 = 0.f, v01 = 0.f, v11 = 0.f;
    bool vx0 = (unsigned)x0 < 64u, vx1 = (unsigned)(x0 + 1) < 64u;
    if ((unsigned)y0 < 64u) {
        if (vx0) v00 = xp[y0 * 64 + x0];
        if (vx1) v10 = xp[y0 * 64 + x0 + 1];
    }
    if ((unsigned)(y0 + 1) < 64u) {
        if (vx0) v01 = xp[(y0 + 1) * 64 + x0];
        if (vx1) v11 = xp[(y0 + 1) * 64 + x0 + 1];
    }
    out[id] = v00 * (1.f - wx) * (1.f - wy) + v10 * wx * (1.f - wy)
            + v01 * (1.f - wx) * wy + v11 * wx * wy;
}

// ---------------------------------------------------------------------------
extern "C" void kernel_launch(void* const* d_in, const int* in_sizes, int n_in,
                              void* d_out, int out_size, void* d_ws, size_t ws_size,
                              hipStream_t stream)
{
    (void)in_sizes; (void)n_in; (void)out_size; (void)ws_size;
    const float* inputs = (const float*)d_in[0];
    const float* W1  = (const float*)d_in[1];
    const float* b1  = (const float*)d_in[2];
    const float* W2  = (const float*)d_in[3];
    const float* b2  = (const float*)d_in[4];
    const float* Wum = (const float*)d_in[5];
    const float* bum = (const float*)d_in[6];
    const float* Wuv = (const float*)d_in[7];
    const float* buv = (const float*)d_in[8];
    const float* Wgm = (const float*)d_in[9];
    const float* bgm = (const float*)d_in[10];
    const float* Wgv = (const float*)d_in[11];
    const float* bgv = (const float*)d_in[12];
    const float* Wz  = (const float*)d_in[13];
    const float* Mm  = (const float*)d_in[14];
    const float* eps_u = (const float*)d_in[15];
    const float* eps_g = (const float*)d_in[16];

    float* ws = (float*)d_ws;
    float* psum      = ws;                     // 2,097,152 (8 x 256x1024)
    float* hid2      = ws + 2097152;           // 262,144
    float* x_buf     = ws + 2359296;           // 1,048,576
    float* u_buf     = ws + 3407872;           // 12,288
    float* gu_buf    = ws + 3420160;           // 768
    float* parts_buf = ws + 3420928;           // 4,096
    float* WTh_buf   = ws + 3425024;           // 104,448 (head weights)
    unsigned short* us = (unsigned short*)(ws + 3529472);
    unsigned short* Ahi   = us;                 // 1,048,576
    unsigned short* Alo   = Ahi + 1048576;
    unsigned short* W1Thi = Alo + 1048576;      // 4,194,304
    unsigned short* W1Tlo = W1Thi + 4194304;
    unsigned short* W2Thi = W1Tlo + 4194304;    // 1,048,576
    unsigned short* W2Tlo = W2Thi + 1048576;
    unsigned short* H1hi  = W2Tlo + 1048576;    // 262,144
    unsigned short* H1lo  = H1hi + 262144;

    // Input conversions (independent)
    convert_a<<<4096, 256, 0, stream>>>(inputs, Ahi, Alo);               // 256x4096
    convert_wt<<<dim3(32, 128), 256, 0, stream>>>(W1, W1Thi, W1Tlo, 4096);
    convert_wt<<<dim3(32, 32), 256, 0, stream>>>(W2, W2Thi, W2Tlo, 1024);
    transpose_heads<<<408, 256, 0, stream>>>(Wum, Wuv, Wgm, Wgv, WTh_buf);
    parts_kernel<<<16, 256, 0, stream>>>(Wz, parts_buf);

    // MLP layer 1: [256,4096] @ [4096,1024], bf16x3 MFMA split-K
    gemm_bf16x3<<<dim3(16, 4, SPLITK), 256, 0, stream>>>(Ahi, Alo, W1Thi, W1Tlo,
                                                         psum, 4096, 4096 / SPLITK);
    reduce_bias_relu_split<<<1024, 256, 0, stream>>>(psum, b1, H1hi, H1lo);
    // MLP layer 2: [256,1024] @ [1024,1024]
    gemm_bf16x3<<<dim3(16, 4, SPLITK), 256, 0, stream>>>(H1hi, H1lo, W2Thi, W2Tlo,
                                                         psum, 1024, 1024 / SPLITK);
    reduce_bias_relu<<<1024, 256, 0, stream>>>(psum, b2, hid2);
    // Heads -> u [256,48], gu [256,3]
    heads_compute<<<128, 512, 0, stream>>>(hid2, WTh_buf, bum, buv, bgm, bgv,
                                           eps_u, eps_g, u_buf, gu_buf);
    // Masked compositing -> x [256,64,64]
    composite_v3<<<1024, 256, 0, stream>>>(Mm, parts_buf, u_buf, x_buf);
    // Global transform -> out [256,1,64,64]
    final_kernel<<<4096, 256, 0, stream>>>(x_buf, gu_buf, (float*)d_out);
}

// Round 5
// 250.119 us; speedup vs baseline: 1.5440x; 1.0363x over previous
//
#include <hip/hip_runtime.h>
#include <math.h>

// Problem constants: B=256, H=W=64, P=16, PH=PW=16, ZD=32, HD=1024, UD=3, IN=4096
#define SPLITK 8

typedef __bf16 bf16x8 __attribute__((ext_vector_type(8)));
typedef float  f32x4  __attribute__((ext_vector_type(4)));

__device__ inline unsigned short bf16rne(float x) {
    unsigned int u = __float_as_uint(x);
    unsigned int r = u + 0x7FFFu + ((u >> 16) & 1u);
    return (unsigned short)(r >> 16);
}
__device__ inline float bf16tof(unsigned short h) {
    return __uint_as_float(((unsigned int)h) << 16);
}

// ---------------------------------------------------------------------------
// prep_all: fused independent preprocessing.
//  blocks [0,4096)      : W1 [4096,1024] -> W1T{hi,lo} [1024,4096] transposed split
//  blocks [4096,8192)   : inputs fp32 -> Ahi/Alo bf16 split (elementwise)
//  blocks [8192,9216)   : W2 [1024,1024] -> W2T{hi,lo} [1024,1024]
//  blocks [9216,9624)   : head weights -> k-major WT[102][1024] fp32
//  blocks [9624,9640)   : parts = sigmoid(colsum Wz) [4096]
// ---------------------------------------------------------------------------
__global__ __launch_bounds__(256) void prep_all(
    const float* __restrict__ inputs,
    const float* __restrict__ W1, const float* __restrict__ W2,
    const float* __restrict__ Wum, const float* __restrict__ Wuv,
    const float* __restrict__ Wgm, const float* __restrict__ Wgv,
    const float* __restrict__ Wz,
    unsigned short* __restrict__ Ahi, unsigned short* __restrict__ Alo,
    unsigned short* __restrict__ W1Thi, unsigned short* __restrict__ W1Tlo,
    unsigned short* __restrict__ W2Thi, unsigned short* __restrict__ W2Tlo,
    float* __restrict__ WT, float* __restrict__ partsb)
{
    __shared__ float t[32][33];
    int bid = blockIdx.x;
    int tid = threadIdx.x;
    if (bid < 4096 || (bid >= 8192 && bid < 9216)) {
        // transpose+split a 32x32 tile of W [K,1024] -> WT [1024,K]
        const float* W = (bid < 4096) ? W1 : W2;
        unsigned short* Thi = (bid < 4096) ? W1Thi : W2Thi;
        unsigned short* Tlo = (bid < 4096) ? W1Tlo : W2Tlo;
        int K = (bid < 4096) ? 4096 : 1024;
        int b2 = (bid < 4096) ? bid : (bid - 8192);
        int n0 = (b2 & 31) * 32, k0 = (b2 >> 5) * 32;
        int c = tid & 31, r0 = tid >> 5;
#pragma unroll
        for (int i = 0; i < 4; i++)
            t[r0 + 8 * i][c] = W[(size_t)(k0 + r0 + 8 * i) * 1024 + n0 + c];
        __syncthreads();
        int kk = tid & 31, n1 = tid >> 5;
#pragma unroll
        for (int i = 0; i < 4; i++) {
            float x = t[kk][n1 + 8 * i];
            unsigned short h = bf16rne(x);
            unsigned short l = bf16rne(x - bf16tof(h));
            size_t o = (size_t)(n0 + n1 + 8 * i) * K + k0 + kk;
            Thi[o] = h;
            Tlo[o] = l;
        }
    } else if (bid < 8192) {
        int id = (bid - 4096) * 256 + tid;     // 1,048,576 elements
        float x = inputs[id];
        unsigned short h = bf16rne(x);
        Ahi[id] = h;
        Alo[id] = bf16rne(x - bf16tof(h));
    } else if (bid < 9624) {
        int id = (bid - 9216) * 256 + tid;     // 104,448
        int o = id >> 10;
        int k = id & 1023;
        float v;
        if (o < 48)       v = Wum[k * 48 + o];
        else if (o < 96)  v = Wuv[k * 48 + (o - 48)];
        else if (o < 99)  v = Wgm[k * 3 + (o - 96)];
        else              v = Wgv[k * 3 + (o - 99)];
        WT[id] = v;
    } else {
        int idx = (bid - 9624) * 256 + tid;    // 4096
        float s = 0.f;
#pragma unroll
        for (int z = 0; z < 32; z++) s += Wz[z * 4096 + idx];
        partsb[idx] = 1.f / (1.f + expf(-s));
    }
}

// ---------------------------------------------------------------------------
// GEMM bf16x3 (fp32-accurate): psum[z] = A[256,Kc] @ B^T-tiles.
// C = Ahi*Bhi + Ahi*Blo + Alo*Bhi, MFMA 16x16x32_bf16.
// Block: 64x64 tile, 256 thr = 4 waves (2x2), each wave 32x32 (2x2 frags).
// grid = (N/64=16, M/64=4, SPLITK).  kchunk % 64 == 0.
// ---------------------------------------------------------------------------
__global__ __launch_bounds__(256) void gemm_bf16x3(
    const unsigned short* __restrict__ Ahi, const unsigned short* __restrict__ Alo,
    const unsigned short* __restrict__ Bhi, const unsigned short* __restrict__ Blo,
    float* __restrict__ psum, int K, int kchunk)
{
    __shared__ unsigned short Ah[4096], Al[4096], Bh[4096], Bl[4096];
    int tid = threadIdx.x;
    int n0 = blockIdx.x * 64, m0 = blockIdx.y * 64;
    int kb = blockIdx.z * kchunk;
    int wid = tid >> 6, lane = tid & 63;
    int wm = wid & 1, wn = wid >> 1;
    int lm = lane & 15, q = lane >> 4;

    int r0 = tid >> 3, ch0 = tid & 7;
    int r1 = (tid + 256) >> 3, ch1 = (tid + 256) & 7;
    int l0 = r0 * 64 + 8 * (ch0 ^ (r0 & 7));
    int l1 = r1 * 64 + 8 * (ch1 ^ (r1 & 7));
    size_t ga0 = (size_t)(m0 + r0) * K + kb + ch0 * 8;
    size_t ga1 = (size_t)(m0 + r1) * K + kb + ch1 * 8;
    size_t gb0 = (size_t)(n0 + r0) * K + kb + ch0 * 8;
    size_t gb1 = (size_t)(n0 + r1) * K + kb + ch1 * 8;

    f32x4 acc[2][2] = {};

    int nkt = kchunk >> 6;
    uint4 vah0, vah1, val0, val1, vbh0, vbh1, vbl0, vbl1;
    vah0 = *(const uint4*)(Ahi + ga0);
    vah1 = *(const uint4*)(Ahi + ga1);
    val0 = *(const uint4*)(Alo + ga0);
    val1 = *(const uint4*)(Alo + ga1);
    vbh0 = *(const uint4*)(Bhi + gb0);
    vbh1 = *(const uint4*)(Bhi + gb1);
    vbl0 = *(const uint4*)(Blo + gb0);
    vbl1 = *(const uint4*)(Blo + gb1);

    int frm0 = (wm * 32 + lm) * 64;
    int frm1 = (wm * 32 + 16 + lm) * 64;
    int frn0 = (wn * 32 + lm) * 64;
    int frn1 = (wn * 32 + 16 + lm) * 64;
    int sw = lm & 7;

    for (int kt = 0; kt < nkt; kt++) {
        __syncthreads();
        *(uint4*)(Ah + l0) = vah0;
        *(uint4*)(Ah + l1) = vah1;
        *(uint4*)(Al + l0) = val0;
        *(uint4*)(Al + l1) = val1;
        *(uint4*)(Bh + l0) = vbh0;
        *(uint4*)(Bh + l1) = vbh1;
        *(uint4*)(Bl + l0) = vbl0;
        *(uint4*)(Bl + l1) = vbl1;
        __syncthreads();
        if (kt + 1 < nkt) {
            size_t o = (size_t)(kt + 1) * 64;
            vah0 = *(const uint4*)(Ahi + ga0 + o);
            vah1 = *(const uint4*)(Ahi + ga1 + o);
            val0 = *(const uint4*)(Alo + ga0 + o);
            val1 = *(const uint4*)(Alo + ga1 + o);
            vbh0 = *(const uint4*)(Bhi + gb0 + o);
            vbh1 = *(const uint4*)(Bhi + gb1 + o);
            vbl0 = *(const uint4*)(Blo + gb0 + o);
            vbl1 = *(const uint4*)(Blo + gb1 + o);
        }
#pragma unroll
        for (int ks = 0; ks < 2; ks++) {
            int cidx = 8 * (((ks << 2) + q) ^ sw);
            bf16x8 ah0 = *(const bf16x8*)(Ah + frm0 + cidx);
            bf16x8 ah1 = *(const bf16x8*)(Ah + frm1 + cidx);
            bf16x8 al0 = *(const bf16x8*)(Al + frm0 + cidx);
            bf16x8 al1 = *(const bf16x8*)(Al + frm1 + cidx);
            bf16x8 bh0 = *(const bf16x8*)(Bh + frn0 + cidx);
            bf16x8 bh1 = *(const bf16x8*)(Bh + frn1 + cidx);
            bf16x8 bl0 = *(const bf16x8*)(Bl + frn0 + cidx);
            bf16x8 bl1 = *(const bf16x8*)(Bl + frn1 + cidx);
            acc[0][0] = __builtin_amdgcn_mfma_f32_16x16x32_bf16(ah0, bh0, acc[0][0], 0, 0, 0);
            acc[0][0] = __builtin_amdgcn_mfma_f32_16x16x32_bf16(ah0, bl0, acc[0][0], 0, 0, 0);
            acc[0][0] = __builtin_amdgcn_mfma_f32_16x16x32_bf16(al0, bh0, acc[0][0], 0, 0, 0);
            acc[0][1] = __builtin_amdgcn_mfma_f32_16x16x32_bf16(ah0, bh1, acc[0][1], 0, 0, 0);
            acc[0][1] = __builtin_amdgcn_mfma_f32_16x16x32_bf16(ah0, bl1, acc[0][1], 0, 0, 0);
            acc[0][1] = __builtin_amdgcn_mfma_f32_16x16x32_bf16(al0, bh1, acc[0][1], 0, 0, 0);
            acc[1][0] = __builtin_amdgcn_mfma_f32_16x16x32_bf16(ah1, bh0, acc[1][0], 0, 0, 0);
            acc[1][0] = __builtin_amdgcn_mfma_f32_16x16x32_bf16(ah1, bl0, acc[1][0], 0, 0, 0);
            acc[1][0] = __builtin_amdgcn_mfma_f32_16x16x32_bf16(al1, bh0, acc[1][0], 0, 0, 0);
            acc[1][1] = __builtin_amdgcn_mfma_f32_16x16x32_bf16(ah1, bh1, acc[1][1], 0, 0, 0);
            acc[1][1] = __builtin_amdgcn_mfma_f32_16x16x32_bf16(ah1, bl1, acc[1][1], 0, 0, 0);
            acc[1][1] = __builtin_amdgcn_mfma_f32_16x16x32_bf16(al1, bh1, acc[1][1], 0, 0, 0);
        }
    }

    // Epilogue: C/D layout col = lane&15, row = q*4 + reg
    float* op = psum + (size_t)blockIdx.z * (256 * 1024);
#pragma unroll
    for (int mt = 0; mt < 2; mt++)
#pragma unroll
        for (int nt = 0; nt < 2; nt++) {
            int row = m0 + wm * 32 + mt * 16 + q * 4;
            int col = n0 + wn * 32 + nt * 16 + lm;
#pragma unroll
            for (int r = 0; r < 4; r++)
                op[(size_t)(row + r) * 1024 + col] = acc[mt][nt][r];
        }
}

// ---------------------------------------------------------------------------
// Reduce split-K partials + bias + relu -> fp32 out.
// ---------------------------------------------------------------------------
__global__ __launch_bounds__(256) void reduce_bias_relu(
    const float* __restrict__ psum, const float* __restrict__ bias,
    float* __restrict__ out)
{
    int i = blockIdx.x * 256 + threadIdx.x;
    float v = 0.f;
#pragma unroll
    for (int s = 0; s < SPLITK; s++) v += psum[(size_t)s * 262144 + i];
    v += bias[i & 1023];
    out[i] = fmaxf(v, 0.f);
}

// Same, but emit bf16 hi/lo split (feeds layer-2 GEMM).
__global__ __launch_bounds__(256) void reduce_bias_relu_split(
    const float* __restrict__ psum, const float* __restrict__ bias,
    unsigned short* __restrict__ hi, unsigned short* __restrict__ lo)
{
    int i = blockIdx.x * 256 + threadIdx.x;
    float v = 0.f;
#pragma unroll
    for (int s = 0; s < SPLITK; s++) v += psum[(size_t)s * 262144 + i];
    v += bias[i & 1023];
    v = fmaxf(v, 0.f);
    unsigned short h = bf16rne(v);
    hi[i] = h;
    lo[i] = bf16rne(v - bf16tof(h));
}

// ---------------------------------------------------------------------------
// Heads: wave-per-output-pair, coalesced k-major weights, shfl reduce.
// ---------------------------------------------------------------------------
__global__ __launch_bounds__(512) void heads_compute(
    const float* __restrict__ hid, const float* __restrict__ WT,
    const float* __restrict__ bum, const float* __restrict__ buv,
    const float* __restrict__ bgm, const float* __restrict__ bgv,
    const float* __restrict__ eps_u, const float* __restrict__ eps_g,
    float* __restrict__ u_out, float* __restrict__ gu_out)
{
    __shared__ float h[2048];
    int b0 = blockIdx.x << 1;
    int tid = threadIdx.x;
    const float* hp = hid + b0 * 1024;
    for (int i = tid; i < 2048; i += 512) h[i] = hp[i];
    __syncthreads();
    int w = tid >> 6, l = tid & 63;
    for (int o = w; o < 51; o += 8) {
        int rm = (o < 48) ? o : (48 + o);
        int rv = (o < 48) ? (o + 48) : (51 + o);
        const float* wmp = WT + rm * 1024;
        const float* wvp = WT + rv * 1024;
        float am0 = 0.f, am1 = 0.f, av0 = 0.f, av1 = 0.f;
#pragma unroll
        for (int j0 = 0; j0 < 1024; j0 += 64) {
            int j = j0 + l;
            float wm = wmp[j], wv = wvp[j];
            float h0 = h[j], h1 = h[1024 + j];
            am0 = fmaf(h0, wm, am0);
            am1 = fmaf(h1, wm, am1);
            av0 = fmaf(h0, wv, av0);
            av1 = fmaf(h1, wv, av1);
        }
#pragma unroll
        for (int s = 32; s; s >>= 1) {
            am0 += __shfl_xor(am0, s, 64);
            am1 += __shfl_xor(am1, s, 64);
            av0 += __shfl_xor(av0, s, 64);
            av1 += __shfl_xor(av1, s, 64);
        }
        if (l < 2) {
            float am = l ? am1 : am0;
            float av = l ? av1 : av0;
            int b = b0 + l;
            if (o < 48) {
                float umu = tanhf(am + bum[o]);
                float uvar = expf(fmaxf(av + buv[o], -6.f));  // threshold(-6,-6)
                u_out[b * 48 + o] = umu + uvar * eps_u[b * 48 + o];
            } else {
                int n = o - 48;
                float gmu = tanhf(am + bgm[n]);
                float gpre = av + bgv[n];
                float gvar = expf(gpre > -6.f ? gpre : 6.f);  // threshold(-6,6)
                gu_out[b * 3 + n] = gmu + gvar * eps_g[b * 3 + n];
            }
        }
    }
}

// ---------------------------------------------------------------------------
// Composite v5: halo staging. 512 blocks = (batch, row-half), 256 threads,
// 8 rows/thread. Per plane p only the 33 source rows this half needs are
// staged (row window is block-uniform: iY = floor(32*ty)+dy). Register
// prefetch double-pipelined across p. Total M traffic ~ unique (67 MB).
// ---------------------------------------------------------------------------
__global__ __launch_bounds__(256) void composite_v5(
    const float* __restrict__ M, const float* __restrict__ parts,
    const float* __restrict__ u, float* __restrict__ xout)
{
    __shared__ float patch[4096];
    __shared__ float plane[33 * 64];     // halo window
    __shared__ float pc[16], psn[16], ptx[16], pty[16];
    int b = blockIdx.x >> 1;
    int half = blockIdx.x & 1;
    int tid = threadIdx.x;
    int brow0 = half * 32;

    for (int i = tid; i < 4096; i += 256) patch[i] = parts[i];
    if (tid < 16) {
        const float* up = u + (b * 16 + tid) * 3;
        float ang = up[0];
        pc[tid] = cosf(ang);
        psn[tid] = sinf(ang);
        ptx[tid] = up[1];
        pty[tid] = up[2];
    }
    __syncthreads();   // params visible (needed to compute prefetch windows)

    int j = tid & 63;
    int i0 = brow0 + (tid >> 6) * 8;
    float xnv = (float)(2 * j + 1) * (1.f / 64.f) - 1.f;

    float num[8] = {}, den[8] = {};
    const float* Mb = M + ((size_t)(b * 16) << 12);

    // helper lambdas (inlined)
    auto calc_iy = [&](int p, int& iy, int& iY, float& wy) {
        int dy = 8 * (p >> 2) - 12;
        float ay = fminf(fmaxf(32.f * pty[p], -16384.f), 16384.f);
        float fay = floorf(ay);
        wy = ay - fay;
        iy = (int)fay;
        iY = iy + dy;
    };

    // prefetch plane window for p=0
    int iy_c, iY_c; float wy_c;
    calc_iy(0, iy_c, iY_c, wy_c);
    float4 pf0, pf1, pf2;
    {
        const float* Mp = Mb;
        int lo = brow0 + iY_c;
        int rr0 = tid >> 4,           c0 = tid & 15;
        int rr1 = (tid + 256) >> 4,   c1 = (tid + 256) & 15;
        int rr2 = (tid + 512) >> 4,   c2 = (tid + 512) & 15;
        pf0 = *(const float4*)(Mp + (min(max(lo + rr0, 0), 63) << 6) + c0 * 4);
        pf1 = *(const float4*)(Mp + (min(max(lo + rr1, 0), 63) << 6) + c1 * 4);
        if (tid < 16)
            pf2 = *(const float4*)(Mp + (min(max(lo + rr2, 0), 63) << 6) + c2 * 4);
    }

    for (int p = 0; p < 16; p++) {
        {
            float4* dst = (float4*)plane;
            dst[tid] = pf0;
            dst[tid + 256] = pf1;
            if (tid < 16) dst[tid + 512] = pf2;
        }
        __syncthreads();
        int iy = iy_c, iY = iY_c; float wy = wy_c;
        if (p < 15) {
            calc_iy(p + 1, iy_c, iY_c, wy_c);
            const float* Mp = Mb + ((size_t)(p + 1) << 12);
            int lo = brow0 + iY_c;
            int rr0 = tid >> 4,           c0 = tid & 15;
            int rr1 = (tid + 256) >> 4,   c1 = (tid + 256) & 15;
            int rr2 = (tid + 512) >> 4,   c2 = (tid + 512) & 15;
            pf0 = *(const float4*)(Mp + (min(max(lo + rr0, 0), 63) << 6) + c0 * 4);
            pf1 = *(const float4*)(Mp + (min(max(lo + rr1, 0), 63) << 6) + c1 * 4);
            if (tid < 16)
                pf2 = *(const float4*)(Mp + (min(max(lo + rr2, 0), 63) << 6) + c2 * 4);
        }

        int dx = 8 * (p & 3) - 12;
        float c = pc[p], s = psn[p], tx = ptx[p], ty = pty[p];
        (void)ty;

        // km column blend (weights constant per (b,p))
        float ax = fminf(fmaxf(32.f * tx, -16384.f), 16384.f);
        float fax = floorf(ax);
        float wx = ax - fax;
        int ix = (int)fax;

        int x0 = j + ix;
        int X = x0 + dx;
        bool vc0 = ((unsigned)x0 < 64u) && ((unsigned)X < 64u);
        bool vc1 = ((unsigned)(x0 + 1) < 64u) && ((unsigned)(X + 1) < 64u);
        float w0 = vc0 ? (1.f - wx) : 0.f;
        float w1 = vc1 ? wx : 0.f;
        int Xc0 = min(max(X, 0), 63);
        int Xc1 = min(max(X + 1, 0), 63);

        float R[9];
#pragma unroll
        for (int r = 0; r < 9; r++) {
            int i = i0 + r;
            int y0i = i + iy;                  // image row of corner
            int ri = i + iY;                   // source plane row
            bool vr = ((unsigned)y0i < 64u) && ((unsigned)ri < 64u);
            int lrow = (tid >> 6) * 8 + r;     // = ri - (brow0 + iY), in [0,32]
            const float* row = plane + (lrow << 6);
            float val = fmaf(w0, row[Xc0], w1 * row[Xc1]);
            R[r] = vr ? val : 0.f;
        }

        // xp: rotated sample of 16x16 patch
        float Ax = fmaf(c, xnv, tx);
        float Ay = fmaf(s, xnv, ptx[p] * 0.f + pty[p]);   // s*xn + ty
        int ox = 24 - dx, oy = 24 - (8 * (p >> 2) - 12);
        const float* pp = patch + (p << 8);
#pragma unroll
        for (int r = 0; r < 8; r++) {
            int i = i0 + r;
            float km = fmaf(wy, R[r + 1] - R[r], R[r]);
            den[r] += km;

            float ynv = (float)(2 * i + 1) * (1.f / 64.f) - 1.f;
            float gx = fmaf(-s, ynv, Ax);
            float gy = fmaf(c, ynv, Ay);
            gx = fminf(fmaxf(gx, -8.f), 8.f);
            gy = fminf(fmaxf(gy, -8.f), 8.f);
            float xs = fmaf(gx, 32.f, 31.5f);
            float ysv = fmaf(gy, 32.f, 31.5f);
            float xf = floorf(xs), yf = floorf(ysv);
            float wxx = xs - xf, wyy = ysv - yf;
            int a0 = (int)yf - oy;
            int b0c = (int)xf - ox;
            if ((unsigned)(a0 + 1) <= 16u && (unsigned)(b0c + 1) <= 16u) {
                float v00 = 0.f, v10 = 0.f, v01 = 0.f, v11 = 0.f;
                if ((unsigned)a0 < 16u) {
                    const float* pr = pp + a0 * 16;
                    if ((unsigned)b0c < 16u) v00 = pr[b0c];
                    if ((unsigned)(b0c + 1) < 16u) v10 = pr[b0c + 1];
                }
                if ((unsigned)(a0 + 1) < 16u) {
                    const float* pr = pp + (a0 + 1) * 16;
                    if ((unsigned)b0c < 16u) v01 = pr[b0c];
                    if ((unsigned)(b0c + 1) < 16u) v11 = pr[b0c + 1];
                }
                float top = fmaf(wxx, v10 - v00, v00);
                float bot = fmaf(wxx, v11 - v01, v01);
                float xp = fmaf(wyy, bot - top, top);
                num[r] = fmaf(xp, km, num[r]);
            }
        }
        __syncthreads();
    }

    float* xo = xout + ((size_t)b << 12);
#pragma unroll
    for (int r = 0; r < 8; r++) {
        float d = (den[r] == 0.f) ? 1.f : den[r];
        xo[(i0 + r) * 64 + j] = num[r] / d;
    }
}

// ---------------------------------------------------------------------------
// Final global transform: out[b] = bilinear(x[b], rot_tr(gu[b]) grid)
// ---------------------------------------------------------------------------
__global__ __launch_bounds__(256) void final_kernel(
    const float* __restrict__ xin, const float* __restrict__ gu,
    float* __restrict__ out)
{
    int id = blockIdx.x * 256 + threadIdx.x;  // 1048576
    int b = id >> 12;
    int pix = id & 4095;
    int ii = pix >> 6, jj = pix & 63;
    float ang = gu[b * 3 + 0], tx = gu[b * 3 + 1], ty = gu[b * 3 + 2];
    float c = cosf(ang), s = sinf(ang);
    float xn = (float)(2 * jj + 1) * (1.f / 64.f) - 1.f;
    float yn = (float)(2 * ii + 1) * (1.f / 64.f) - 1.f;
    float gx = c * xn - s * yn + tx;
    float gy = s * xn + c * yn + ty;
    float xs = (gx + 1.f) * 32.f - 0.5f;
    float ysv = (gy + 1.f) * 32.f - 0.5f;
    float xf = floorf(xs), yf = floorf(ysv);
    float wx = xs - xf, wy = ysv - yf;
    int x0 = (int)xf, y0 = (int)yf;
    const float* xp = xin + ((size_t)b << 12);
    float v00 = 0.f, v10 = 0.f, v01 = 0.f, v11 = 0.f;
    bool vx0 = (unsigned)x0 < 64u, vx1 = (unsigned)(x0 + 1) < 64u;
    if ((unsigned)y0 < 64u) {
        if (vx0) v00 = xp[y0 * 64 + x0];
        if (vx1) v10 = xp[y0 * 64 + x0 + 1];
    }
    if ((unsigned)(y0 + 1) < 64u) {
        if (vx0) v01 = xp[(y0 + 1) * 64 + x0];
        if (vx1) v11 = xp[(y0 + 1) * 64 + x0 + 1];
    }
    out[id] = v00 * (1.f - wx) * (1.f - wy) + v10 * wx * (1.f - wy)
            + v01 * (1.f - wx) * wy + v11 * wx * wy;
}

// ---------------------------------------------------------------------------
extern "C" void kernel_launch(void* const* d_in, const int* in_sizes, int n_in,
                              void* d_out, int out_size, void* d_ws, size_t ws_size,
                              hipStream_t stream)
{
    (void)in_sizes; (void)n_in; (void)out_size; (void)ws_size;
    const float* inputs = (const float*)d_in[0];
    const float* W1  = (const float*)d_in[1];
    const float* b1  = (const float*)d_in[2];
    const float* W2  = (const float*)d_in[3];
    const float* b2  = (const float*)d_in[4];
    const float* Wum = (const float*)d_in[5];
    const float* bum = (const float*)d_in[6];
    const float* Wuv = (const float*)d_in[7];
    const float* buv = (const float*)d_in[8];
    const float* Wgm = (const float*)d_in[9];
    const float* bgm = (const float*)d_in[10];
    const float* Wgv = (const float*)d_in[11];
    const float* bgv = (const float*)d_in[12];
    const float* Wz  = (const float*)d_in[13];
    const float* Mm  = (const float*)d_in[14];
    const float* eps_u = (const float*)d_in[15];
    const float* eps_g = (const float*)d_in[16];

    float* ws = (float*)d_ws;
    float* psum      = ws;                     // 2,097,152 (8 x 256x1024)
    float* hid2      = ws + 2097152;           // 262,144
    float* x_buf     = ws + 2359296;           // 1,048,576
    float* u_buf     = ws + 3407872;           // 12,288
    float* gu_buf    = ws + 3420160;           // 768
    float* parts_buf = ws + 3420928;           // 4,096
    float* WTh_buf   = ws + 3425024;           // 104,448 (head weights)
    unsigned short* us = (unsigned short*)(ws + 3529472);
    unsigned short* Ahi   = us;                 // 1,048,576
    unsigned short* Alo   = Ahi + 1048576;
    unsigned short* W1Thi = Alo + 1048576;      // 4,194,304
    unsigned short* W1Tlo = W1Thi + 4194304;
    unsigned short* W2Thi = W1Tlo + 4194304;    // 1,048,576
    unsigned short* W2Tlo = W2Thi + 1048576;
    unsigned short* H1hi  = W2Tlo + 1048576;    // 262,144
    unsigned short* H1lo  = H1hi + 262144;

    // All independent preprocessing in ONE dispatch
    prep_all<<<9640, 256, 0, stream>>>(inputs, W1, W2, Wum, Wuv, Wgm, Wgv, Wz,
                                       Ahi, Alo, W1Thi, W1Tlo, W2Thi, W2Tlo,
                                       WTh_buf, parts_buf);

    // MLP layer 1: [256,4096] @ [4096,1024], bf16x3 MFMA split-K
    gemm_bf16x3<<<dim3(16, 4, SPLITK), 256, 0, stream>>>(Ahi, Alo, W1Thi, W1Tlo,
                                                         psum, 4096, 4096 / SPLITK);
    reduce_bias_relu_split<<<1024, 256, 0, stream>>>(psum, b1, H1hi, H1lo);
    // MLP layer 2: [256,1024] @ [1024,1024]
    gemm_bf16x3<<<dim3(16, 4, SPLITK), 256, 0, stream>>>(H1hi, H1lo, W2Thi, W2Tlo,
                                                         psum, 1024, 1024 / SPLITK);
    reduce_bias_relu<<<1024, 256, 0, stream>>>(psum, b2, hid2);
    // Heads -> u [256,48], gu [256,3]
    heads_compute<<<128, 512, 0, stream>>>(hid2, WTh_buf, bum, buv, bgm, bgv,
                                           eps_u, eps_g, u_buf, gu_buf);
    // Masked compositing -> x [256,64,64]
    composite_v5<<<512, 256, 0, stream>>>(Mm, parts_buf, u_buf, x_buf);
    // Global transform -> out [256,1,64,64]
    final_kernel<<<4096, 256, 0, stream>>>(x_buf, gu_buf, (float*)d_out);
}

// Round 6
// 221.580 us; speedup vs baseline: 1.7428x; 1.1288x over previous
//
#include <hip/hip_runtime.h>
#include <math.h>

// Problem constants: B=256, H=W=64, P=16, PH=PW=16, ZD=32, HD=1024, UD=3, IN=4096
#define SPLITK 8

typedef __bf16 bf16x8 __attribute__((ext_vector_type(8)));
typedef float  f32x4  __attribute__((ext_vector_type(4)));

__device__ inline unsigned short bf16rne(float x) {
    unsigned int u = __float_as_uint(x);
    unsigned int r = u + 0x7FFFu + ((u >> 16) & 1u);
    return (unsigned short)(r >> 16);
}
__device__ inline float bf16tof(unsigned short h) {
    return __uint_as_float(((unsigned int)h) << 16);
}

// ---------------------------------------------------------------------------
// prep_all: fused independent preprocessing.
//  blocks [0,4096)      : W1 [4096,1024] -> W1T{hi,lo} [1024,4096] transposed split
//  blocks [4096,8192)   : inputs fp32 -> Ahi/Alo bf16 split (elementwise)
//  blocks [8192,9216)   : W2 [1024,1024] -> W2T{hi,lo} [1024,1024]
//  blocks [9216,9624)   : head weights -> k-major WT[102][1024] fp32
//  blocks [9624,9640)   : parts = sigmoid(colsum Wz) [4096]
// ---------------------------------------------------------------------------
__global__ __launch_bounds__(256) void prep_all(
    const float* __restrict__ inputs,
    const float* __restrict__ W1, const float* __restrict__ W2,
    const float* __restrict__ Wum, const float* __restrict__ Wuv,
    const float* __restrict__ Wgm, const float* __restrict__ Wgv,
    const float* __restrict__ Wz,
    unsigned short* __restrict__ Ahi, unsigned short* __restrict__ Alo,
    unsigned short* __restrict__ W1Thi, unsigned short* __restrict__ W1Tlo,
    unsigned short* __restrict__ W2Thi, unsigned short* __restrict__ W2Tlo,
    float* __restrict__ WT, float* __restrict__ partsb)
{
    __shared__ float t[32][33];
    int bid = blockIdx.x;
    int tid = threadIdx.x;
    if (bid < 4096 || (bid >= 8192 && bid < 9216)) {
        const float* W = (bid < 4096) ? W1 : W2;
        unsigned short* Thi = (bid < 4096) ? W1Thi : W2Thi;
        unsigned short* Tlo = (bid < 4096) ? W1Tlo : W2Tlo;
        int K = (bid < 4096) ? 4096 : 1024;
        int b2 = (bid < 4096) ? bid : (bid - 8192);
        int n0 = (b2 & 31) * 32, k0 = (b2 >> 5) * 32;
        int c = tid & 31, r0 = tid >> 5;
#pragma unroll
        for (int i = 0; i < 4; i++)
            t[r0 + 8 * i][c] = W[(size_t)(k0 + r0 + 8 * i) * 1024 + n0 + c];
        __syncthreads();
        int kk = tid & 31, n1 = tid >> 5;
#pragma unroll
        for (int i = 0; i < 4; i++) {
            float x = t[kk][n1 + 8 * i];
            unsigned short h = bf16rne(x);
            unsigned short l = bf16rne(x - bf16tof(h));
            size_t o = (size_t)(n0 + n1 + 8 * i) * K + k0 + kk;
            Thi[o] = h;
            Tlo[o] = l;
        }
    } else if (bid < 8192) {
        int id = (bid - 4096) * 256 + tid;
        float x = inputs[id];
        unsigned short h = bf16rne(x);
        Ahi[id] = h;
        Alo[id] = bf16rne(x - bf16tof(h));
    } else if (bid < 9624) {
        int id = (bid - 9216) * 256 + tid;
        int o = id >> 10;
        int k = id & 1023;
        float v;
        if (o < 48)       v = Wum[k * 48 + o];
        else if (o < 96)  v = Wuv[k * 48 + (o - 48)];
        else if (o < 99)  v = Wgm[k * 3 + (o - 96)];
        else              v = Wgv[k * 3 + (o - 99)];
        WT[id] = v;
    } else {
        int idx = (bid - 9624) * 256 + tid;
        float s = 0.f;
#pragma unroll
        for (int z = 0; z < 32; z++) s += Wz[z * 4096 + idx];
        partsb[idx] = 1.f / (1.f + expf(-s));
    }
}

// ---------------------------------------------------------------------------
// GEMM bf16x3 (fp32-accurate): psum[z] = A[256,Kc] @ B^T-tiles.
// ---------------------------------------------------------------------------
__global__ __launch_bounds__(256) void gemm_bf16x3(
    const unsigned short* __restrict__ Ahi, const unsigned short* __restrict__ Alo,
    const unsigned short* __restrict__ Bhi, const unsigned short* __restrict__ Blo,
    float* __restrict__ psum, int K, int kchunk)
{
    __shared__ unsigned short Ah[4096], Al[4096], Bh[4096], Bl[4096];
    int tid = threadIdx.x;
    int n0 = blockIdx.x * 64, m0 = blockIdx.y * 64;
    int kb = blockIdx.z * kchunk;
    int wid = tid >> 6, lane = tid & 63;
    int wm = wid & 1, wn = wid >> 1;
    int lm = lane & 15, q = lane >> 4;

    int r0 = tid >> 3, ch0 = tid & 7;
    int r1 = (tid + 256) >> 3, ch1 = (tid + 256) & 7;
    int l0 = r0 * 64 + 8 * (ch0 ^ (r0 & 7));
    int l1 = r1 * 64 + 8 * (ch1 ^ (r1 & 7));
    size_t ga0 = (size_t)(m0 + r0) * K + kb + ch0 * 8;
    size_t ga1 = (size_t)(m0 + r1) * K + kb + ch1 * 8;
    size_t gb0 = (size_t)(n0 + r0) * K + kb + ch0 * 8;
    size_t gb1 = (size_t)(n0 + r1) * K + kb + ch1 * 8;

    f32x4 acc[2][2] = {};

    int nkt = kchunk >> 6;
    uint4 vah0, vah1, val0, val1, vbh0, vbh1, vbl0, vbl1;
    vah0 = *(const uint4*)(Ahi + ga0);
    vah1 = *(const uint4*)(Ahi + ga1);
    val0 = *(const uint4*)(Alo + ga0);
    val1 = *(const uint4*)(Alo + ga1);
    vbh0 = *(const uint4*)(Bhi + gb0);
    vbh1 = *(const uint4*)(Bhi + gb1);
    vbl0 = *(const uint4*)(Blo + gb0);
    vbl1 = *(const uint4*)(Blo + gb1);

    int frm0 = (wm * 32 + lm) * 64;
    int frm1 = (wm * 32 + 16 + lm) * 64;
    int frn0 = (wn * 32 + lm) * 64;
    int frn1 = (wn * 32 + 16 + lm) * 64;
    int sw = lm & 7;

    for (int kt = 0; kt < nkt; kt++) {
        __syncthreads();
        *(uint4*)(Ah + l0) = vah0;
        *(uint4*)(Ah + l1) = vah1;
        *(uint4*)(Al + l0) = val0;
        *(uint4*)(Al + l1) = val1;
        *(uint4*)(Bh + l0) = vbh0;
        *(uint4*)(Bh + l1) = vbh1;
        *(uint4*)(Bl + l0) = vbl0;
        *(uint4*)(Bl + l1) = vbl1;
        __syncthreads();
        if (kt + 1 < nkt) {
            size_t o = (size_t)(kt + 1) * 64;
            vah0 = *(const uint4*)(Ahi + ga0 + o);
            vah1 = *(const uint4*)(Ahi + ga1 + o);
            val0 = *(const uint4*)(Alo + ga0 + o);
            val1 = *(const uint4*)(Alo + ga1 + o);
            vbh0 = *(const uint4*)(Bhi + gb0 + o);
            vbh1 = *(const uint4*)(Bhi + gb1 + o);
            vbl0 = *(const uint4*)(Blo + gb0 + o);
            vbl1 = *(const uint4*)(Blo + gb1 + o);
        }
#pragma unroll
        for (int ks = 0; ks < 2; ks++) {
            int cidx = 8 * (((ks << 2) + q) ^ sw);
            bf16x8 ah0 = *(const bf16x8*)(Ah + frm0 + cidx);
            bf16x8 ah1 = *(const bf16x8*)(Ah + frm1 + cidx);
            bf16x8 al0 = *(const bf16x8*)(Al + frm0 + cidx);
            bf16x8 al1 = *(const bf16x8*)(Al + frm1 + cidx);
            bf16x8 bh0 = *(const bf16x8*)(Bh + frn0 + cidx);
            bf16x8 bh1 = *(const bf16x8*)(Bh + frn1 + cidx);
            bf16x8 bl0 = *(const bf16x8*)(Bl + frn0 + cidx);
            bf16x8 bl1 = *(const bf16x8*)(Bl + frn1 + cidx);
            acc[0][0] = __builtin_amdgcn_mfma_f32_16x16x32_bf16(ah0, bh0, acc[0][0], 0, 0, 0);
            acc[0][0] = __builtin_amdgcn_mfma_f32_16x16x32_bf16(ah0, bl0, acc[0][0], 0, 0, 0);
            acc[0][0] = __builtin_amdgcn_mfma_f32_16x16x32_bf16(al0, bh0, acc[0][0], 0, 0, 0);
            acc[0][1] = __builtin_amdgcn_mfma_f32_16x16x32_bf16(ah0, bh1, acc[0][1], 0, 0, 0);
            acc[0][1] = __builtin_amdgcn_mfma_f32_16x16x32_bf16(ah0, bl1, acc[0][1], 0, 0, 0);
            acc[0][1] = __builtin_amdgcn_mfma_f32_16x16x32_bf16(al0, bh1, acc[0][1], 0, 0, 0);
            acc[1][0] = __builtin_amdgcn_mfma_f32_16x16x32_bf16(ah1, bh0, acc[1][0], 0, 0, 0);
            acc[1][0] = __builtin_amdgcn_mfma_f32_16x16x32_bf16(ah1, bl0, acc[1][0], 0, 0, 0);
            acc[1][0] = __builtin_amdgcn_mfma_f32_16x16x32_bf16(al1, bh0, acc[1][0], 0, 0, 0);
            acc[1][1] = __builtin_amdgcn_mfma_f32_16x16x32_bf16(ah1, bh1, acc[1][1], 0, 0, 0);
            acc[1][1] = __builtin_amdgcn_mfma_f32_16x16x32_bf16(ah1, bl1, acc[1][1], 0, 0, 0);
            acc[1][1] = __builtin_amdgcn_mfma_f32_16x16x32_bf16(al1, bh1, acc[1][1], 0, 0, 0);
        }
    }

    float* op = psum + (size_t)blockIdx.z * (256 * 1024);
#pragma unroll
    for (int mt = 0; mt < 2; mt++)
#pragma unroll
        for (int nt = 0; nt < 2; nt++) {
            int row = m0 + wm * 32 + mt * 16 + q * 4;
            int col = n0 + wn * 32 + nt * 16 + lm;
#pragma unroll
            for (int r = 0; r < 4; r++)
                op[(size_t)(row + r) * 1024 + col] = acc[mt][nt][r];
        }
}

// ---------------------------------------------------------------------------
// Reduce split-K partials + bias + relu -> fp32 out.
// ---------------------------------------------------------------------------
__global__ __launch_bounds__(256) void reduce_bias_relu(
    const float* __restrict__ psum, const float* __restrict__ bias,
    float* __restrict__ out)
{
    int i = blockIdx.x * 256 + threadIdx.x;
    float v = 0.f;
#pragma unroll
    for (int s = 0; s < SPLITK; s++) v += psum[(size_t)s * 262144 + i];
    v += bias[i & 1023];
    out[i] = fmaxf(v, 0.f);
}

// Same, but emit bf16 hi/lo split (feeds layer-2 GEMM).
__global__ __launch_bounds__(256) void reduce_bias_relu_split(
    const float* __restrict__ psum, const float* __restrict__ bias,
    unsigned short* __restrict__ hi, unsigned short* __restrict__ lo)
{
    int i = blockIdx.x * 256 + threadIdx.x;
    float v = 0.f;
#pragma unroll
    for (int s = 0; s < SPLITK; s++) v += psum[(size_t)s * 262144 + i];
    v += bias[i & 1023];
    v = fmaxf(v, 0.f);
    unsigned short h = bf16rne(v);
    hi[i] = h;
    lo[i] = bf16rne(v - bf16tof(h));
}

// ---------------------------------------------------------------------------
// heads_v2: 256 blocks (1 batch), 8 waves; wave w does o = w, w+8, ...
// Lane l holds h[k] for k = i*256 + l*4 + {0..3} in REGISTERS (loaded once).
// Per o: 8 independent float4 weight loads (software-pipelined one o ahead),
// 32 FMAs, 6-step shfl butterfly, lane 0 finishes.
// ---------------------------------------------------------------------------
__global__ __launch_bounds__(512) void heads_v2(
    const float* __restrict__ hid, const float* __restrict__ WT,
    const float* __restrict__ bum, const float* __restrict__ buv,
    const float* __restrict__ bgm, const float* __restrict__ bgv,
    const float* __restrict__ eps_u, const float* __restrict__ eps_g,
    float* __restrict__ u_out, float* __restrict__ gu_out)
{
    int b = blockIdx.x;
    int tid = threadIdx.x;
    int w = tid >> 6, l = tid & 63;

    const float* hp = hid + b * 1024 + l * 4;
    float4 hr[4];
#pragma unroll
    for (int i = 0; i < 4; i++) hr[i] = *(const float4*)(hp + i * 256);

    int o = w;
    int rm = (o < 48) ? o : (48 + o);
    int rv = (o < 48) ? (o + 48) : (51 + o);
    float4 wm[4], wv[4];
    {
        const float* wp = WT + rm * 1024 + l * 4;
#pragma unroll
        for (int i = 0; i < 4; i++) wm[i] = *(const float4*)(wp + i * 256);
        wp = WT + rv * 1024 + l * 4;
#pragma unroll
        for (int i = 0; i < 4; i++) wv[i] = *(const float4*)(wp + i * 256);
    }

    while (o < 51) {
        int onext = o + 8;
        float4 wmn[4], wvn[4];
        if (onext < 51) {
            int rm2 = (onext < 48) ? onext : (48 + onext);
            int rv2 = (onext < 48) ? (onext + 48) : (51 + onext);
            const float* wp = WT + rm2 * 1024 + l * 4;
#pragma unroll
            for (int i = 0; i < 4; i++) wmn[i] = *(const float4*)(wp + i * 256);
            wp = WT + rv2 * 1024 + l * 4;
#pragma unroll
            for (int i = 0; i < 4; i++) wvn[i] = *(const float4*)(wp + i * 256);
        }
        float am = 0.f, av = 0.f;
#pragma unroll
        for (int i = 0; i < 4; i++) {
            am = fmaf(hr[i].x, wm[i].x, am);
            am = fmaf(hr[i].y, wm[i].y, am);
            am = fmaf(hr[i].z, wm[i].z, am);
            am = fmaf(hr[i].w, wm[i].w, am);
            av = fmaf(hr[i].x, wv[i].x, av);
            av = fmaf(hr[i].y, wv[i].y, av);
            av = fmaf(hr[i].z, wv[i].z, av);
            av = fmaf(hr[i].w, wv[i].w, av);
        }
#pragma unroll
        for (int s = 32; s; s >>= 1) {
            am += __shfl_xor(am, s, 64);
            av += __shfl_xor(av, s, 64);
        }
        if (l == 0) {
            if (o < 48) {
                float umu = tanhf(am + bum[o]);
                float uvar = expf(fmaxf(av + buv[o], -6.f));  // threshold(-6,-6)
                u_out[b * 48 + o] = umu + uvar * eps_u[b * 48 + o];
            } else {
                int n = o - 48;
                float gmu = tanhf(am + bgm[n]);
                float gpre = av + bgv[n];
                float gvar = expf(gpre > -6.f ? gpre : 6.f);  // threshold(-6,6)
                gu_out[b * 3 + n] = gmu + gvar * eps_g[b * 3 + n];
            }
        }
#pragma unroll
        for (int i = 0; i < 4; i++) { wm[i] = wmn[i]; wv[i] = wvn[i]; }
        o = onext;
    }
}

// ---------------------------------------------------------------------------
// Composite v5: halo staging. 512 blocks = (batch, row-half), 256 threads,
// 8 rows/thread. Per plane p only the 33 source rows this half needs are
// staged. Register prefetch double-pipelined across p.
// ---------------------------------------------------------------------------
__global__ __launch_bounds__(256) void composite_v5(
    const float* __restrict__ M, const float* __restrict__ parts,
    const float* __restrict__ u, float* __restrict__ xout)
{
    __shared__ float patch[4096];
    __shared__ float plane[33 * 64];
    __shared__ float pc[16], psn[16], ptx[16], pty[16];
    int b = blockIdx.x >> 1;
    int half = blockIdx.x & 1;
    int tid = threadIdx.x;
    int brow0 = half * 32;

    for (int i = tid; i < 4096; i += 256) patch[i] = parts[i];
    if (tid < 16) {
        const float* up = u + (b * 16 + tid) * 3;
        float ang = up[0];
        pc[tid] = cosf(ang);
        psn[tid] = sinf(ang);
        ptx[tid] = up[1];
        pty[tid] = up[2];
    }
    __syncthreads();

    int j = tid & 63;
    int i0 = brow0 + (tid >> 6) * 8;
    float xnv = (float)(2 * j + 1) * (1.f / 64.f) - 1.f;

    float num[8] = {}, den[8] = {};
    const float* Mb = M + ((size_t)(b * 16) << 12);

    auto calc_iy = [&](int p, int& iy, int& iY, float& wy) {
        int dy = 8 * (p >> 2) - 12;
        float ay = fminf(fmaxf(32.f * pty[p], -16384.f), 16384.f);
        float fay = floorf(ay);
        wy = ay - fay;
        iy = (int)fay;
        iY = iy + dy;
    };

    int iy_c, iY_c; float wy_c;
    calc_iy(0, iy_c, iY_c, wy_c);
    float4 pf0, pf1, pf2;
    {
        const float* Mp = Mb;
        int lo = brow0 + iY_c;
        int rr0 = tid >> 4,           c0 = tid & 15;
        int rr1 = (tid + 256) >> 4,   c1 = (tid + 256) & 15;
        int rr2 = (tid + 512) >> 4,   c2 = (tid + 512) & 15;
        pf0 = *(const float4*)(Mp + (min(max(lo + rr0, 0), 63) << 6) + c0 * 4);
        pf1 = *(const float4*)(Mp + (min(max(lo + rr1, 0), 63) << 6) + c1 * 4);
        if (tid < 16)
            pf2 = *(const float4*)(Mp + (min(max(lo + rr2, 0), 63) << 6) + c2 * 4);
    }

    for (int p = 0; p < 16; p++) {
        {
            float4* dst = (float4*)plane;
            dst[tid] = pf0;
            dst[tid + 256] = pf1;
            if (tid < 16) dst[tid + 512] = pf2;
        }
        __syncthreads();
        int iy = iy_c, iY = iY_c; float wy = wy_c;
        if (p < 15) {
            calc_iy(p + 1, iy_c, iY_c, wy_c);
            const float* Mp = Mb + ((size_t)(p + 1) << 12);
            int lo = brow0 + iY_c;
            int rr0 = tid >> 4,           c0 = tid & 15;
            int rr1 = (tid + 256) >> 4,   c1 = (tid + 256) & 15;
            int rr2 = (tid + 512) >> 4,   c2 = (tid + 512) & 15;
            pf0 = *(const float4*)(Mp + (min(max(lo + rr0, 0), 63) << 6) + c0 * 4);
            pf1 = *(const float4*)(Mp + (min(max(lo + rr1, 0), 63) << 6) + c1 * 4);
            if (tid < 16)
                pf2 = *(const float4*)(Mp + (min(max(lo + rr2, 0), 63) << 6) + c2 * 4);
        }

        int dx = 8 * (p & 3) - 12;
        float c = pc[p], s = psn[p], tx = ptx[p];

        float ax = fminf(fmaxf(32.f * tx, -16384.f), 16384.f);
        float fax = floorf(ax);
        float wx = ax - fax;
        int ix = (int)fax;

        int x0 = j + ix;
        int X = x0 + dx;
        bool vc0 = ((unsigned)x0 < 64u) && ((unsigned)X < 64u);
        bool vc1 = ((unsigned)(x0 + 1) < 64u) && ((unsigned)(X + 1) < 64u);
        float w0 = vc0 ? (1.f - wx) : 0.f;
        float w1 = vc1 ? wx : 0.f;
        int Xc0 = min(max(X, 0), 63);
        int Xc1 = min(max(X + 1, 0), 63);

        float R[9];
#pragma unroll
        for (int r = 0; r < 9; r++) {
            int i = i0 + r;
            int y0i = i + iy;
            int ri = i + iY;
            bool vr = ((unsigned)y0i < 64u) && ((unsigned)ri < 64u);
            int lrow = (tid >> 6) * 8 + r;
            const float* row = plane + (lrow << 6);
            float val = fmaf(w0, row[Xc0], w1 * row[Xc1]);
            R[r] = vr ? val : 0.f;
        }

        float Ax = fmaf(c, xnv, tx);
        float Ay = fmaf(s, xnv, pty[p]);
        int ox = 24 - dx, oy = 24 - (8 * (p >> 2) - 12);
        const float* pp = patch + (p << 8);
#pragma unroll
        for (int r = 0; r < 8; r++) {
            int i = i0 + r;
            float km = fmaf(wy, R[r + 1] - R[r], R[r]);
            den[r] += km;

            float ynv = (float)(2 * i + 1) * (1.f / 64.f) - 1.f;
            float gx = fmaf(-s, ynv, Ax);
            float gy = fmaf(c, ynv, Ay);
            gx = fminf(fmaxf(gx, -8.f), 8.f);
            gy = fminf(fmaxf(gy, -8.f), 8.f);
            float xs = fmaf(gx, 32.f, 31.5f);
            float ysv = fmaf(gy, 32.f, 31.5f);
            float xf = floorf(xs), yf = floorf(ysv);
            float wxx = xs - xf, wyy = ysv - yf;
            int a0 = (int)yf - oy;
            int b0c = (int)xf - ox;
            if ((unsigned)(a0 + 1) <= 16u && (unsigned)(b0c + 1) <= 16u) {
                float v00 = 0.f, v10 = 0.f, v01 = 0.f, v11 = 0.f;
                if ((unsigned)a0 < 16u) {
                    const float* pr = pp + a0 * 16;
                    if ((unsigned)b0c < 16u) v00 = pr[b0c];
                    if ((unsigned)(b0c + 1) < 16u) v10 = pr[b0c + 1];
                }
                if ((unsigned)(a0 + 1) < 16u) {
                    const float* pr = pp + (a0 + 1) * 16;
                    if ((unsigned)b0c < 16u) v01 = pr[b0c];
                    if ((unsigned)(b0c + 1) < 16u) v11 = pr[b0c + 1];
                }
                float top = fmaf(wxx, v10 - v00, v00);
                float bot = fmaf(wxx, v11 - v01, v01);
                float xp = fmaf(wyy, bot - top, top);
                num[r] = fmaf(xp, km, num[r]);
            }
        }
        __syncthreads();
    }

    float* xo = xout + ((size_t)b << 12);
#pragma unroll
    for (int r = 0; r < 8; r++) {
        float d = (den[r] == 0.f) ? 1.f : den[r];
        xo[(i0 + r) * 64 + j] = num[r] / d;
    }
}

// ---------------------------------------------------------------------------
// Final global transform: out[b] = bilinear(x[b], rot_tr(gu[b]) grid)
// ---------------------------------------------------------------------------
__global__ __launch_bounds__(256) void final_kernel(
    const float* __restrict__ xin, const float* __restrict__ gu,
    float* __restrict__ out)
{
    int id = blockIdx.x * 256 + threadIdx.x;  // 1048576
    int b = id >> 12;
    int pix = id & 4095;
    int ii = pix >> 6, jj = pix & 63;
    float ang = gu[b * 3 + 0], tx = gu[b * 3 + 1], ty = gu[b * 3 + 2];
    float c = cosf(ang), s = sinf(ang);
    float xn = (float)(2 * jj + 1) * (1.f / 64.f) - 1.f;
    float yn = (float)(2 * ii + 1) * (1.f / 64.f) - 1.f;
    float gx = c * xn - s * yn + tx;
    float gy = s * xn + c * yn + ty;
    float xs = (gx + 1.f) * 32.f - 0.5f;
    float ysv = (gy + 1.f) * 32.f - 0.5f;
    float xf = floorf(xs), yf = floorf(ysv);
    float wx = xs - xf, wy = ysv - yf;
    int x0 = (int)xf, y0 = (int)yf;
    const float* xp = xin + ((size_t)b << 12);
    float v00 = 0.f, v10 = 0.f, v01 = 0.f, v11 = 0.f;
    bool vx0 = (unsigned)x0 < 64u, vx1 = (unsigned)(x0 + 1) < 64u;
    if ((unsigned)y0 < 64u) {
        if (vx0) v00 = xp[y0 * 64 + x0];
        if (vx1) v10 = xp[y0 * 64 + x0 + 1];
    }
    if ((unsigned)(y0 + 1) < 64u) {
        if (vx0) v01 = xp[(y0 + 1) * 64 + x0];
        if (vx1) v11 = xp[(y0 + 1) * 64 + x0 + 1];
    }
    out[id] = v00 * (1.f - wx) * (1.f - wy) + v10 * wx * (1.f - wy)
            + v01 * (1.f - wx) * wy + v11 * wx * wy;
}

// ---------------------------------------------------------------------------
extern "C" void kernel_launch(void* const* d_in, const int* in_sizes, int n_in,
                              void* d_out, int out_size, void* d_ws, size_t ws_size,
                              hipStream_t stream)
{
    (void)in_sizes; (void)n_in; (void)out_size; (void)ws_size;
    const float* inputs = (const float*)d_in[0];
    const float* W1  = (const float*)d_in[1];
    const float* b1  = (const float*)d_in[2];
    const float* W2  = (const float*)d_in[3];
    const float* b2  = (const float*)d_in[4];
    const float* Wum = (const float*)d_in[5];
    const float* bum = (const float*)d_in[6];
    const float* Wuv = (const float*)d_in[7];
    const float* buv = (const float*)d_in[8];
    const float* Wgm = (const float*)d_in[9];
    const float* bgm = (const float*)d_in[10];
    const float* Wgv = (const float*)d_in[11];
    const float* bgv = (const float*)d_in[12];
    const float* Wz  = (const float*)d_in[13];
    const float* Mm  = (const float*)d_in[14];
    const float* eps_u = (const float*)d_in[15];
    const float* eps_g = (const float*)d_in[16];

    float* ws = (float*)d_ws;
    float* psum      = ws;                     // 2,097,152 (8 x 256x1024)
    float* hid2      = ws + 2097152;           // 262,144
    float* x_buf     = ws + 2359296;           // 1,048,576
    float* u_buf     = ws + 3407872;           // 12,288
    float* gu_buf    = ws + 3420160;           // 768
    float* parts_buf = ws + 3420928;           // 4,096
    float* WTh_buf   = ws + 3425024;           // 104,448 (head weights)
    unsigned short* us = (unsigned short*)(ws + 3529472);
    unsigned short* Ahi   = us;                 // 1,048,576
    unsigned short* Alo   = Ahi + 1048576;
    unsigned short* W1Thi = Alo + 1048576;      // 4,194,304
    unsigned short* W1Tlo = W1Thi + 4194304;
    unsigned short* W2Thi = W1Tlo + 4194304;    // 1,048,576
    unsigned short* W2Tlo = W2Thi + 1048576;
    unsigned short* H1hi  = W2Tlo + 1048576;    // 262,144
    unsigned short* H1lo  = H1hi + 262144;

    // All independent preprocessing in ONE dispatch
    prep_all<<<9640, 256, 0, stream>>>(inputs, W1, W2, Wum, Wuv, Wgm, Wgv, Wz,
                                       Ahi, Alo, W1Thi, W1Tlo, W2Thi, W2Tlo,
                                       WTh_buf, parts_buf);

    // MLP layer 1: [256,4096] @ [4096,1024], bf16x3 MFMA split-K
    gemm_bf16x3<<<dim3(16, 4, SPLITK), 256, 0, stream>>>(Ahi, Alo, W1Thi, W1Tlo,
                                                         psum, 4096, 4096 / SPLITK);
    reduce_bias_relu_split<<<1024, 256, 0, stream>>>(psum, b1, H1hi, H1lo);
    // MLP layer 2: [256,1024] @ [1024,1024]
    gemm_bf16x3<<<dim3(16, 4, SPLITK), 256, 0, stream>>>(H1hi, H1lo, W2Thi, W2Tlo,
                                                         psum, 1024, 1024 / SPLITK);
    reduce_bias_relu<<<1024, 256, 0, stream>>>(psum, b2, hid2);
    // Heads -> u [256,48], gu [256,3]
    heads_v2<<<256, 512, 0, stream>>>(hid2, WTh_buf, bum, buv, bgm, bgv,
                                      eps_u, eps_g, u_buf, gu_buf);
    // Masked compositing -> x [256,64,64]
    composite_v5<<<512, 256, 0, stream>>>(Mm, parts_buf, u_buf, x_buf);
    // Global transform -> out [256,1,64,64]
    final_kernel<<<4096, 256, 0, stream>>>(x_buf, gu_buf, (float*)d_out);
}

// Round 7
// 210.230 us; speedup vs baseline: 1.8369x; 1.0540x over previous
//
#include <hip/hip_runtime.h>
#include <math.h>

// Problem constants: B=256, H=W=64, P=16, PH=PW=16, ZD=32, HD=1024, UD=3, IN=4096
#define SPLITK 8

typedef __bf16 bf16x8 __attribute__((ext_vector_type(8)));
typedef float  f32x4  __attribute__((ext_vector_type(4)));

__device__ inline unsigned short bf16rne(float x) {
    unsigned int u = __float_as_uint(x);
    unsigned int r = u + 0x7FFFu + ((u >> 16) & 1u);
    return (unsigned short)(r >> 16);
}
__device__ inline float bf16tof(unsigned short h) {
    return __uint_as_float(((unsigned int)h) << 16);
}

// ---------------------------------------------------------------------------
// prep_all: fused independent preprocessing.
//  blocks [0,4096)      : W1 [4096,1024] -> W1T{hi,lo} [1024,4096] transposed split
//  blocks [4096,8192)   : inputs fp32 -> Ahi/Alo bf16 split (elementwise)
//  blocks [8192,9216)   : W2 [1024,1024] -> W2T{hi,lo} [1024,1024]
//  blocks [9216,9624)   : head weights -> k-major WT[102][1024] fp32
//  blocks [9624,9640)   : parts = sigmoid(colsum Wz) [4096]
// ---------------------------------------------------------------------------
__global__ __launch_bounds__(256) void prep_all(
    const float* __restrict__ inputs,
    const float* __restrict__ W1, const float* __restrict__ W2,
    const float* __restrict__ Wum, const float* __restrict__ Wuv,
    const float* __restrict__ Wgm, const float* __restrict__ Wgv,
    const float* __restrict__ Wz,
    unsigned short* __restrict__ Ahi, unsigned short* __restrict__ Alo,
    unsigned short* __restrict__ W1Thi, unsigned short* __restrict__ W1Tlo,
    unsigned short* __restrict__ W2Thi, unsigned short* __restrict__ W2Tlo,
    float* __restrict__ WT, float* __restrict__ partsb)
{
    __shared__ float t[32][33];
    int bid = blockIdx.x;
    int tid = threadIdx.x;
    if (bid < 4096 || (bid >= 8192 && bid < 9216)) {
        const float* W = (bid < 4096) ? W1 : W2;
        unsigned short* Thi = (bid < 4096) ? W1Thi : W2Thi;
        unsigned short* Tlo = (bid < 4096) ? W1Tlo : W2Tlo;
        int K = (bid < 4096) ? 4096 : 1024;
        int b2 = (bid < 4096) ? bid : (bid - 8192);
        int n0 = (b2 & 31) * 32, k0 = (b2 >> 5) * 32;
        int c = tid & 31, r0 = tid >> 5;
#pragma unroll
        for (int i = 0; i < 4; i++)
            t[r0 + 8 * i][c] = W[(size_t)(k0 + r0 + 8 * i) * 1024 + n0 + c];
        __syncthreads();
        int kk = tid & 31, n1 = tid >> 5;
#pragma unroll
        for (int i = 0; i < 4; i++) {
            float x = t[kk][n1 + 8 * i];
            unsigned short h = bf16rne(x);
            unsigned short l = bf16rne(x - bf16tof(h));
            size_t o = (size_t)(n0 + n1 + 8 * i) * K + k0 + kk;
            Thi[o] = h;
            Tlo[o] = l;
        }
    } else if (bid < 8192) {
        int id = (bid - 4096) * 256 + tid;
        float x = inputs[id];
        unsigned short h = bf16rne(x);
        Ahi[id] = h;
        Alo[id] = bf16rne(x - bf16tof(h));
    } else if (bid < 9624) {
        int id = (bid - 9216) * 256 + tid;
        int o = id >> 10;
        int k = id & 1023;
        float v;
        if (o < 48)       v = Wum[k * 48 + o];
        else if (o < 96)  v = Wuv[k * 48 + (o - 48)];
        else if (o < 99)  v = Wgm[k * 3 + (o - 96)];
        else              v = Wgv[k * 3 + (o - 99)];
        WT[id] = v;
    } else {
        int idx = (bid - 9624) * 256 + tid;
        float s = 0.f;
#pragma unroll
        for (int z = 0; z < 32; z++) s += Wz[z * 4096 + idx];
        partsb[idx] = 1.f / (1.f + expf(-s));
    }
}

// ---------------------------------------------------------------------------
// GEMM bf16x3 (fp32-accurate): psum[z] = A[256,Kc] @ B^T-tiles.
// ---------------------------------------------------------------------------
__global__ __launch_bounds__(256) void gemm_bf16x3(
    const unsigned short* __restrict__ Ahi, const unsigned short* __restrict__ Alo,
    const unsigned short* __restrict__ Bhi, const unsigned short* __restrict__ Blo,
    float* __restrict__ psum, int K, int kchunk)
{
    __shared__ unsigned short Ah[4096], Al[4096], Bh[4096], Bl[4096];
    int tid = threadIdx.x;
    int n0 = blockIdx.x * 64, m0 = blockIdx.y * 64;
    int kb = blockIdx.z * kchunk;
    int wid = tid >> 6, lane = tid & 63;
    int wm = wid & 1, wn = wid >> 1;
    int lm = lane & 15, q = lane >> 4;

    int r0 = tid >> 3, ch0 = tid & 7;
    int r1 = (tid + 256) >> 3, ch1 = (tid + 256) & 7;
    int l0 = r0 * 64 + 8 * (ch0 ^ (r0 & 7));
    int l1 = r1 * 64 + 8 * (ch1 ^ (r1 & 7));
    size_t ga0 = (size_t)(m0 + r0) * K + kb + ch0 * 8;
    size_t ga1 = (size_t)(m0 + r1) * K + kb + ch1 * 8;
    size_t gb0 = (size_t)(n0 + r0) * K + kb + ch0 * 8;
    size_t gb1 = (size_t)(n0 + r1) * K + kb + ch1 * 8;

    f32x4 acc[2][2] = {};

    int nkt = kchunk >> 6;
    uint4 vah0, vah1, val0, val1, vbh0, vbh1, vbl0, vbl1;
    vah0 = *(const uint4*)(Ahi + ga0);
    vah1 = *(const uint4*)(Ahi + ga1);
    val0 = *(const uint4*)(Alo + ga0);
    val1 = *(const uint4*)(Alo + ga1);
    vbh0 = *(const uint4*)(Bhi + gb0);
    vbh1 = *(const uint4*)(Bhi + gb1);
    vbl0 = *(const uint4*)(Blo + gb0);
    vbl1 = *(const uint4*)(Blo + gb1);

    int frm0 = (wm * 32 + lm) * 64;
    int frm1 = (wm * 32 + 16 + lm) * 64;
    int frn0 = (wn * 32 + lm) * 64;
    int frn1 = (wn * 32 + 16 + lm) * 64;
    int sw = lm & 7;

    for (int kt = 0; kt < nkt; kt++) {
        __syncthreads();
        *(uint4*)(Ah + l0) = vah0;
        *(uint4*)(Ah + l1) = vah1;
        *(uint4*)(Al + l0) = val0;
        *(uint4*)(Al + l1) = val1;
        *(uint4*)(Bh + l0) = vbh0;
        *(uint4*)(Bh + l1) = vbh1;
        *(uint4*)(Bl + l0) = vbl0;
        *(uint4*)(Bl + l1) = vbl1;
        __syncthreads();
        if (kt + 1 < nkt) {
            size_t o = (size_t)(kt + 1) * 64;
            vah0 = *(const uint4*)(Ahi + ga0 + o);
            vah1 = *(const uint4*)(Ahi + ga1 + o);
            val0 = *(const uint4*)(Alo + ga0 + o);
            val1 = *(const uint4*)(Alo + ga1 + o);
            vbh0 = *(const uint4*)(Bhi + gb0 + o);
            vbh1 = *(const uint4*)(Bhi + gb1 + o);
            vbl0 = *(const uint4*)(Blo + gb0 + o);
            vbl1 = *(const uint4*)(Blo + gb1 + o);
        }
#pragma unroll
        for (int ks = 0; ks < 2; ks++) {
            int cidx = 8 * (((ks << 2) + q) ^ sw);
            bf16x8 ah0 = *(const bf16x8*)(Ah + frm0 + cidx);
            bf16x8 ah1 = *(const bf16x8*)(Ah + frm1 + cidx);
            bf16x8 al0 = *(const bf16x8*)(Al + frm0 + cidx);
            bf16x8 al1 = *(const bf16x8*)(Al + frm1 + cidx);
            bf16x8 bh0 = *(const bf16x8*)(Bh + frn0 + cidx);
            bf16x8 bh1 = *(const bf16x8*)(Bh + frn1 + cidx);
            bf16x8 bl0 = *(const bf16x8*)(Bl + frn0 + cidx);
            bf16x8 bl1 = *(const bf16x8*)(Bl + frn1 + cidx);
            acc[0][0] = __builtin_amdgcn_mfma_f32_16x16x32_bf16(ah0, bh0, acc[0][0], 0, 0, 0);
            acc[0][0] = __builtin_amdgcn_mfma_f32_16x16x32_bf16(ah0, bl0, acc[0][0], 0, 0, 0);
            acc[0][0] = __builtin_amdgcn_mfma_f32_16x16x32_bf16(al0, bh0, acc[0][0], 0, 0, 0);
            acc[0][1] = __builtin_amdgcn_mfma_f32_16x16x32_bf16(ah0, bh1, acc[0][1], 0, 0, 0);
            acc[0][1] = __builtin_amdgcn_mfma_f32_16x16x32_bf16(ah0, bl1, acc[0][1], 0, 0, 0);
            acc[0][1] = __builtin_amdgcn_mfma_f32_16x16x32_bf16(al0, bh1, acc[0][1], 0, 0, 0);
            acc[1][0] = __builtin_amdgcn_mfma_f32_16x16x32_bf16(ah1, bh0, acc[1][0], 0, 0, 0);
            acc[1][0] = __builtin_amdgcn_mfma_f32_16x16x32_bf16(ah1, bl0, acc[1][0], 0, 0, 0);
            acc[1][0] = __builtin_amdgcn_mfma_f32_16x16x32_bf16(al1, bh0, acc[1][0], 0, 0, 0);
            acc[1][1] = __builtin_amdgcn_mfma_f32_16x16x32_bf16(ah1, bh1, acc[1][1], 0, 0, 0);
            acc[1][1] = __builtin_amdgcn_mfma_f32_16x16x32_bf16(ah1, bl1, acc[1][1], 0, 0, 0);
            acc[1][1] = __builtin_amdgcn_mfma_f32_16x16x32_bf16(al1, bh1, acc[1][1], 0, 0, 0);
        }
    }

    float* op = psum + (size_t)blockIdx.z * (256 * 1024);
#pragma unroll
    for (int mt = 0; mt < 2; mt++)
#pragma unroll
        for (int nt = 0; nt < 2; nt++) {
            int row = m0 + wm * 32 + mt * 16 + q * 4;
            int col = n0 + wn * 32 + nt * 16 + lm;
#pragma unroll
            for (int r = 0; r < 4; r++)
                op[(size_t)(row + r) * 1024 + col] = acc[mt][nt][r];
        }
}

// ---------------------------------------------------------------------------
// Reduce split-K partials + bias + relu -> fp32 out.
// ---------------------------------------------------------------------------
__global__ __launch_bounds__(256) void reduce_bias_relu(
    const float* __restrict__ psum, const float* __restrict__ bias,
    float* __restrict__ out)
{
    int i = blockIdx.x * 256 + threadIdx.x;
    float v = 0.f;
#pragma unroll
    for (int s = 0; s < SPLITK; s++) v += psum[(size_t)s * 262144 + i];
    v += bias[i & 1023];
    out[i] = fmaxf(v, 0.f);
}

// Same, but emit bf16 hi/lo split (feeds layer-2 GEMM).
__global__ __launch_bounds__(256) void reduce_bias_relu_split(
    const float* __restrict__ psum, const float* __restrict__ bias,
    unsigned short* __restrict__ hi, unsigned short* __restrict__ lo)
{
    int i = blockIdx.x * 256 + threadIdx.x;
    float v = 0.f;
#pragma unroll
    for (int s = 0; s < SPLITK; s++) v += psum[(size_t)s * 262144 + i];
    v += bias[i & 1023];
    v = fmaxf(v, 0.f);
    unsigned short h = bf16rne(v);
    hi[i] = h;
    lo[i] = bf16rne(v - bf16tof(h));
}

// ---------------------------------------------------------------------------
// heads_v2: 256 blocks (1 batch), 8 waves; wave w does o = w, w+8, ...
// Lane-register h fragments, software-pipelined float4 weight loads.
// ---------------------------------------------------------------------------
__global__ __launch_bounds__(512) void heads_v2(
    const float* __restrict__ hid, const float* __restrict__ WT,
    const float* __restrict__ bum, const float* __restrict__ buv,
    const float* __restrict__ bgm, const float* __restrict__ bgv,
    const float* __restrict__ eps_u, const float* __restrict__ eps_g,
    float* __restrict__ u_out, float* __restrict__ gu_out)
{
    int b = blockIdx.x;
    int tid = threadIdx.x;
    int w = tid >> 6, l = tid & 63;

    const float* hp = hid + b * 1024 + l * 4;
    float4 hr[4];
#pragma unroll
    for (int i = 0; i < 4; i++) hr[i] = *(const float4*)(hp + i * 256);

    int o = w;
    int rm = (o < 48) ? o : (48 + o);
    int rv = (o < 48) ? (o + 48) : (51 + o);
    float4 wm[4], wv[4];
    {
        const float* wp = WT + rm * 1024 + l * 4;
#pragma unroll
        for (int i = 0; i < 4; i++) wm[i] = *(const float4*)(wp + i * 256);
        wp = WT + rv * 1024 + l * 4;
#pragma unroll
        for (int i = 0; i < 4; i++) wv[i] = *(const float4*)(wp + i * 256);
    }

    while (o < 51) {
        int onext = o + 8;
        float4 wmn[4], wvn[4];
        if (onext < 51) {
            int rm2 = (onext < 48) ? onext : (48 + onext);
            int rv2 = (onext < 48) ? (onext + 48) : (51 + onext);
            const float* wp = WT + rm2 * 1024 + l * 4;
#pragma unroll
            for (int i = 0; i < 4; i++) wmn[i] = *(const float4*)(wp + i * 256);
            wp = WT + rv2 * 1024 + l * 4;
#pragma unroll
            for (int i = 0; i < 4; i++) wvn[i] = *(const float4*)(wp + i * 256);
        }
        float am = 0.f, av = 0.f;
#pragma unroll
        for (int i = 0; i < 4; i++) {
            am = fmaf(hr[i].x, wm[i].x, am);
            am = fmaf(hr[i].y, wm[i].y, am);
            am = fmaf(hr[i].z, wm[i].z, am);
            am = fmaf(hr[i].w, wm[i].w, am);
            av = fmaf(hr[i].x, wv[i].x, av);
            av = fmaf(hr[i].y, wv[i].y, av);
            av = fmaf(hr[i].z, wv[i].z, av);
            av = fmaf(hr[i].w, wv[i].w, av);
        }
#pragma unroll
        for (int s = 32; s; s >>= 1) {
            am += __shfl_xor(am, s, 64);
            av += __shfl_xor(av, s, 64);
        }
        if (l == 0) {
            if (o < 48) {
                float umu = tanhf(am + bum[o]);
                float uvar = expf(fmaxf(av + buv[o], -6.f));  // threshold(-6,-6)
                u_out[b * 48 + o] = umu + uvar * eps_u[b * 48 + o];
            } else {
                int n = o - 48;
                float gmu = tanhf(am + bgm[n]);
                float gpre = av + bgv[n];
                float gvar = expf(gpre > -6.f ? gpre : 6.f);  // threshold(-6,6)
                gu_out[b * 3 + n] = gmu + gvar * eps_g[b * 3 + n];
            }
        }
#pragma unroll
        for (int i = 0; i < 4; i++) { wm[i] = wmn[i]; wv[i] = wvn[i]; }
        o = onext;
    }
}

// ---------------------------------------------------------------------------
// Composite v6: 1024 blocks = (batch, row-quarter), 256 threads, 4 rows/thr.
// Per plane p only a 17-row halo is staged (traffic stays at unique-M level)
// into DOUBLE-BUFFERED LDS planes: one barrier per iteration, vmcnt waits
// land two compute-phases after issue. 4 blocks/CU vs v5's 2.
// ---------------------------------------------------------------------------
__global__ __launch_bounds__(256) void composite_v6(
    const float* __restrict__ M, const float* __restrict__ parts,
    const float* __restrict__ u, float* __restrict__ xout)
{
    __shared__ float patch[4096];
    __shared__ float plane[2][17 * 64];
    __shared__ float pc[16], psn[16], ptx[16], pty[16];
    int b = blockIdx.x >> 2;
    int quarter = blockIdx.x & 3;
    int tid = threadIdx.x;
    int brow0 = quarter * 16;

    for (int i = tid; i < 4096; i += 256) patch[i] = parts[i];
    if (tid < 16) {
        const float* up = u + (b * 16 + tid) * 3;
        float ang = up[0];
        pc[tid] = cosf(ang);
        psn[tid] = sinf(ang);
        ptx[tid] = up[1];
        pty[tid] = up[2];
    }
    __syncthreads();   // params visible for window computation

    int j = tid & 63;
    int i0 = brow0 + (tid >> 6) * 4;
    float xnv = (float)(2 * j + 1) * (1.f / 64.f) - 1.f;

    float num[4] = {}, den[4] = {};
    const float* Mb = M + ((size_t)(b * 16) << 12);

    auto calc_iy = [&](int p, int& iy, int& iY, float& wy) {
        int dy = 8 * (p >> 2) - 12;
        float ay = fminf(fmaxf(32.f * pty[p], -16384.f), 16384.f);
        float fay = floorf(ay);
        wy = ay - fay;
        iy = (int)fay;
        iY = iy + dy;
    };

    // plane window: 17 rows x 64 cols = 272 float4s; thread stages idx tid
    // (tid<16 also idx 256+tid).
    int rr0 = tid >> 4, c0 = tid & 15;
    int rr1 = (tid + 256) >> 4, c1 = (tid + 256) & 15;

    // iy/iY/wy for planes p and p+1 (rolling)
    int iy_arr[17], iY_arr[17]; float wy_arr[17];
#pragma unroll
    for (int p = 0; p < 16; p++) calc_iy(p, iy_arr[p], iY_arr[p], wy_arr[p]);

    float4 pfA0, pfA1;   // prefetch set A (plane p+1 during iter p)
    // prologue: load plane 0, write buf0, prefetch plane 1
    {
        int lo = brow0 + iY_arr[0];
        pfA0 = *(const float4*)(Mb + (min(max(lo + rr0, 0), 63) << 6) + c0 * 4);
        if (tid < 16)
            pfA1 = *(const float4*)(Mb + (min(max(lo + rr1, 0), 63) << 6) + c1 * 4);
        float4* dst = (float4*)plane[0];
        dst[tid] = pfA0;
        if (tid < 16) dst[tid + 256] = pfA1;
    }
    {
        int lo = brow0 + iY_arr[1];
        const float* Mp = Mb + (1 << 12);
        pfA0 = *(const float4*)(Mp + (min(max(lo + rr0, 0), 63) << 6) + c0 * 4);
        if (tid < 16)
            pfA1 = *(const float4*)(Mp + (min(max(lo + rr1, 0), 63) << 6) + c1 * 4);
    }
    __syncthreads();   // buf0 ready

    for (int p = 0; p < 16; p++) {
        int cur = p & 1;
        // write buf[1-cur] with plane p+1 (prefetched); issue prefetch p+2
        if (p + 1 < 16) {
            float4* dst = (float4*)plane[1 - cur];
            dst[tid] = pfA0;
            if (tid < 16) dst[tid + 256] = pfA1;
        }
        if (p + 2 < 16) {
            int lo = brow0 + iY_arr[p + 2];
            const float* Mp = Mb + ((size_t)(p + 2) << 12);
            pfA0 = *(const float4*)(Mp + (min(max(lo + rr0, 0), 63) << 6) + c0 * 4);
            if (tid < 16)
                pfA1 = *(const float4*)(Mp + (min(max(lo + rr1, 0), 63) << 6) + c1 * 4);
        }

        int iy = iy_arr[p], iY = iY_arr[p];
        float wy = wy_arr[p];
        int dx = 8 * (p & 3) - 12;
        float c = pc[p], s = psn[p], tx = ptx[p];

        float ax = fminf(fmaxf(32.f * tx, -16384.f), 16384.f);
        float fax = floorf(ax);
        float wx = ax - fax;
        int ix = (int)fax;

        int x0 = j + ix;
        int X = x0 + dx;
        bool vc0 = ((unsigned)x0 < 64u) && ((unsigned)X < 64u);
        bool vc1 = ((unsigned)(x0 + 1) < 64u) && ((unsigned)(X + 1) < 64u);
        float w0 = vc0 ? (1.f - wx) : 0.f;
        float w1 = vc1 ? wx : 0.f;
        int Xc0 = min(max(X, 0), 63);
        int Xc1 = min(max(X + 1, 0), 63);

        const float* pl = plane[cur];
        float R[5];
#pragma unroll
        for (int r = 0; r < 5; r++) {
            int i = i0 + r;
            int y0i = i + iy;
            int ri = i + iY;
            bool vr = ((unsigned)y0i < 64u) && ((unsigned)ri < 64u);
            int lrow = (tid >> 6) * 4 + r;          // = ri - (brow0+iY), in [0,16]
            const float* row = pl + (lrow << 6);
            float val = fmaf(w0, row[Xc0], w1 * row[Xc1]);
            R[r] = vr ? val : 0.f;
        }

        float Ax = fmaf(c, xnv, tx);
        float Ay = fmaf(s, xnv, pty[p]);
        int ox = 24 - dx, oy = 24 - (8 * (p >> 2) - 12);
        const float* pp = patch + (p << 8);
#pragma unroll
        for (int r = 0; r < 4; r++) {
            int i = i0 + r;
            float km = fmaf(wy, R[r + 1] - R[r], R[r]);
            den[r] += km;

            float ynv = (float)(2 * i + 1) * (1.f / 64.f) - 1.f;
            float gx = fmaf(-s, ynv, Ax);
            float gy = fmaf(c, ynv, Ay);
            gx = fminf(fmaxf(gx, -8.f), 8.f);
            gy = fminf(fmaxf(gy, -8.f), 8.f);
            float xs = fmaf(gx, 32.f, 31.5f);
            float ysv = fmaf(gy, 32.f, 31.5f);
            float xf = floorf(xs), yf = floorf(ysv);
            float wxx = xs - xf, wyy = ysv - yf;
            int a0 = (int)yf - oy;
            int b0c = (int)xf - ox;
            if ((unsigned)(a0 + 1) <= 16u && (unsigned)(b0c + 1) <= 16u) {
                float v00 = 0.f, v10 = 0.f, v01 = 0.f, v11 = 0.f;
                if ((unsigned)a0 < 16u) {
                    const float* pr = pp + a0 * 16;
                    if ((unsigned)b0c < 16u) v00 = pr[b0c];
                    if ((unsigned)(b0c + 1) < 16u) v10 = pr[b0c + 1];
                }
                if ((unsigned)(a0 + 1) < 16u) {
                    const float* pr = pp + (a0 + 1) * 16;
                    if ((unsigned)b0c < 16u) v01 = pr[b0c];
                    if ((unsigned)(b0c + 1) < 16u) v11 = pr[b0c + 1];
                }
                float top = fmaf(wxx, v10 - v00, v00);
                float bot = fmaf(wxx, v11 - v01, v01);
                float xp = fmaf(wyy, bot - top, top);
                num[r] = fmaf(xp, km, num[r]);
            }
        }
        __syncthreads();   // writes to buf[1-cur] done; reads of buf[cur] done
    }

    float* xo = xout + ((size_t)b << 12);
#pragma unroll
    for (int r = 0; r < 4; r++) {
        float d = (den[r] == 0.f) ? 1.f : den[r];
        xo[(i0 + r) * 64 + j] = num[r] / d;
    }
}

// ---------------------------------------------------------------------------
// Final global transform: out[b] = bilinear(x[b], rot_tr(gu[b]) grid)
// ---------------------------------------------------------------------------
__global__ __launch_bounds__(256) void final_kernel(
    const float* __restrict__ xin, const float* __restrict__ gu,
    float* __restrict__ out)
{
    int id = blockIdx.x * 256 + threadIdx.x;  // 1048576
    int b = id >> 12;
    int pix = id & 4095;
    int ii = pix >> 6, jj = pix & 63;
    float ang = gu[b * 3 + 0], tx = gu[b * 3 + 1], ty = gu[b * 3 + 2];
    float c = cosf(ang), s = sinf(ang);
    float xn = (float)(2 * jj + 1) * (1.f / 64.f) - 1.f;
    float yn = (float)(2 * ii + 1) * (1.f / 64.f) - 1.f;
    float gx = c * xn - s * yn + tx;
    float gy = s * xn + c * yn + ty;
    float xs = (gx + 1.f) * 32.f - 0.5f;
    float ysv = (gy + 1.f) * 32.f - 0.5f;
    float xf = floorf(xs), yf = floorf(ysv);
    float wx = xs - xf, wy = ysv - yf;
    int x0 = (int)xf, y0 = (int)yf;
    const float* xp = xin + ((size_t)b << 12);
    float v00 = 0.f, v10 = 0.f, v01 = 0.f, v11 = 0.f;
    bool vx0 = (unsigned)x0 < 64u, vx1 = (unsigned)(x0 + 1) < 64u;
    if ((unsigned)y0 < 64u) {
        if (vx0) v00 = xp[y0 * 64 + x0];
        if (vx1) v10 = xp[y0 * 64 + x0 + 1];
    }
    if ((unsigned)(y0 + 1) < 64u) {
        if (vx0) v01 = xp[(y0 + 1) * 64 + x0];
        if (vx1) v11 = xp[(y0 + 1) * 64 + x0 + 1];
    }
    out[id] = v00 * (1.f - wx) * (1.f - wy) + v10 * wx * (1.f - wy)
            + v01 * (1.f - wx) * wy + v11 * wx * wy;
}

// ---------------------------------------------------------------------------
extern "C" void kernel_launch(void* const* d_in, const int* in_sizes, int n_in,
                              void* d_out, int out_size, void* d_ws, size_t ws_size,
                              hipStream_t stream)
{
    (void)in_sizes; (void)n_in; (void)out_size; (void)ws_size;
    const float* inputs = (const float*)d_in[0];
    const float* W1  = (const float*)d_in[1];
    const float* b1  = (const float*)d_in[2];
    const float* W2  = (const float*)d_in[3];
    const float* b2  = (const float*)d_in[4];
    const float* Wum = (const float*)d_in[5];
    const float* bum = (const float*)d_in[6];
    const float* Wuv = (const float*)d_in[7];
    const float* buv = (const float*)d_in[8];
    const float* Wgm = (const float*)d_in[9];
    const float* bgm = (const float*)d_in[10];
    const float* Wgv = (const float*)d_in[11];
    const float* bgv = (const float*)d_in[12];
    const float* Wz  = (const float*)d_in[13];
    const float* Mm  = (const float*)d_in[14];
    const float* eps_u = (const float*)d_in[15];
    const float* eps_g = (const float*)d_in[16];

    float* ws = (float*)d_ws;
    float* psum      = ws;                     // 2,097,152 (8 x 256x1024)
    float* hid2      = ws + 2097152;           // 262,144
    float* x_buf     = ws + 2359296;           // 1,048,576
    float* u_buf     = ws + 3407872;           // 12,288
    float* gu_buf    = ws + 3420160;           // 768
    float* parts_buf = ws + 3420928;           // 4,096
    float* WTh_buf   = ws + 3425024;           // 104,448 (head weights)
    unsigned short* us = (unsigned short*)(ws + 3529472);
    unsigned short* Ahi   = us;                 // 1,048,576
    unsigned short* Alo   = Ahi + 1048576;
    unsigned short* W1Thi = Alo + 1048576;      // 4,194,304
    unsigned short* W1Tlo = W1Thi + 4194304;
    unsigned short* W2Thi = W1Tlo + 4194304;    // 1,048,576
    unsigned short* W2Tlo = W2Thi + 1048576;
    unsigned short* H1hi  = W2Tlo + 1048576;    // 262,144
    unsigned short* H1lo  = H1hi + 262144;

    // All independent preprocessing in ONE dispatch
    prep_all<<<9640, 256, 0, stream>>>(inputs, W1, W2, Wum, Wuv, Wgm, Wgv, Wz,
                                       Ahi, Alo, W1Thi, W1Tlo, W2Thi, W2Tlo,
                                       WTh_buf, parts_buf);

    // MLP layer 1: [256,4096] @ [4096,1024], bf16x3 MFMA split-K
    gemm_bf16x3<<<dim3(16, 4, SPLITK), 256, 0, stream>>>(Ahi, Alo, W1Thi, W1Tlo,
                                                         psum, 4096, 4096 / SPLITK);
    reduce_bias_relu_split<<<1024, 256, 0, stream>>>(psum, b1, H1hi, H1lo);
    // MLP layer 2: [256,1024] @ [1024,1024]
    gemm_bf16x3<<<dim3(16, 4, SPLITK), 256, 0, stream>>>(H1hi, H1lo, W2Thi, W2Tlo,
                                                         psum, 1024, 1024 / SPLITK);
    reduce_bias_relu<<<1024, 256, 0, stream>>>(psum, b2, hid2);
    // Heads -> u [256,48], gu [256,3]
    heads_v2<<<256, 512, 0, stream>>>(hid2, WTh_buf, bum, buv, bgm, bgv,
                                      eps_u, eps_g, u_buf, gu_buf);
    // Masked compositing -> x [256,64,64]
    composite_v6<<<1024, 256, 0, stream>>>(Mm, parts_buf, u_buf, x_buf);
    // Global transform -> out [256,1,64,64]
    final_kernel<<<4096, 256, 0, stream>>>(x_buf, gu_buf, (float*)d_out);
}